// Round 4
// baseline (369.459 us; speedup 1.0000x reference)
//
#include <hip/hip_runtime.h>

typedef __bf16 bf16;
typedef bf16 bf16x4_t __attribute__((ext_vector_type(4)));
typedef bf16 bf16x8_t __attribute__((ext_vector_type(8)));
typedef float f32x4_t __attribute__((ext_vector_type(4)));

#define DI __device__ __forceinline__

DI void gload_lds16(const void* g, void* l) {
  __builtin_amdgcn_global_load_lds((const __attribute__((address_space(1))) void*)g,
                                   (__attribute__((address_space(3))) void*)l, 16, 0, 0);
}

DI f32x4_t mfma16(bf16x8_t a, bf16x8_t b, f32x4_t c) {
  return __builtin_amdgcn_mfma_f32_16x16x32_bf16(a, b, c, 0, 0, 0);
}

DI unsigned short bfbits(float f) {
  bf16 h = (bf16)f;
  return __builtin_bit_cast(unsigned short, h);
}

// ---------------- LayerNorm (f32 in -> bf16 out), one row per block ----------------
template<bool DUAL>
__global__ __launch_bounds__(256) void ln_kernel(const float* __restrict__ in,
                                                 const float* __restrict__ gamma,
                                                 const float* __restrict__ beta,
                                                 bf16* __restrict__ out1,
                                                 bf16* __restrict__ out2,
                                                 int rpb, int base) {
  const int row = blockIdx.x;
  const int t = threadIdx.x;
  const float4 v = ((const float4*)(in + (size_t)row * 1024))[t];
  float s = v.x + v.y + v.z + v.w;
  float q = v.x * v.x + v.y * v.y + v.z * v.z + v.w * v.w;
#pragma unroll
  for (int off = 1; off < 64; off <<= 1) {
    s += __shfl_xor(s, off);
    q += __shfl_xor(q, off);
  }
  __shared__ float red[8];
  const int w = t >> 6;
  if ((t & 63) == 0) { red[w] = s; red[w + 4] = q; }
  __syncthreads();
  s = red[0] + red[1] + red[2] + red[3];
  q = red[4] + red[5] + red[6] + red[7];
  const float mu = s * (1.f / 1024.f);
  const float var = q * (1.f / 1024.f) - mu * mu;
  const float rs = rsqrtf(var + 1e-5f);
  const float4 gv = ((const float4*)gamma)[t];
  const float4 bv = ((const float4*)beta)[t];
  bf16x4_t o;
  o[0] = (bf16)((v.x - mu) * rs * gv.x + bv.x);
  o[1] = (bf16)((v.y - mu) * rs * gv.y + bv.y);
  o[2] = (bf16)((v.z - mu) * rs * gv.z + bv.z);
  o[3] = (bf16)((v.w - mu) * rs * gv.w + bv.w);
  const int b = row / rpb, r2 = row % rpb;
  *(bf16x4_t*)(out1 + ((size_t)b * 4160 + base + r2) * 1024 + t * 4) = o;
  if constexpr (DUAL) {
    *(bf16x4_t*)(out2 + (size_t)row * 1024 + t * 4) = o;
  }
}

// ---------------- transpose + cast: W[R][C] f32 -> Wt[C][R] bf16 ----------------
__global__ __launch_bounds__(256) void transpose_cvt(const float* __restrict__ W,
                                                     bf16* __restrict__ Wt, int R, int C) {
  __shared__ float tile[32][33];
  const int tx = threadIdx.x, ty = threadIdx.y;
  const int c0 = blockIdx.x * 32, r0 = blockIdx.y * 32;
#pragma unroll
  for (int j = 0; j < 4; ++j)
    tile[ty + j * 8][tx] = W[(size_t)(r0 + ty + j * 8) * C + c0 + tx];
  __syncthreads();
#pragma unroll
  for (int j = 0; j < 4; ++j)
    Wt[(size_t)(c0 + ty + j * 8) * R + r0 + tx] = (bf16)tile[tx][ty + j * 8];
}

// ---------------- small GEMM (128x128 tile): C = A * Bt^T ----------------
// EPI 0: f32 row-major out. EPI 1: q scatter to [b,h,i,d].
template<int EPI>
__global__ __launch_bounds__(256) void gemm_bt(const bf16* __restrict__ A,
                                               const bf16* __restrict__ Bt,
                                               float* __restrict__ Cf,
                                               bf16* __restrict__ C0,
                                               int M, int N, int K) {
  __shared__ bf16 As[128 * 32];
  __shared__ bf16 Bs[128 * 32];
  const int tid = threadIdx.x;
  const int w = tid >> 6, l = tid & 63;
  const int lg = l >> 4, lr = l & 15;
  const int m0 = blockIdx.y * 128, n0 = blockIdx.x * 128;
  const int wm = w >> 1, wn = w & 1;

  f32x4_t acc[4][4];
#pragma unroll
  for (int i = 0; i < 4; ++i)
#pragma unroll
    for (int j = 0; j < 4; ++j)
      acc[i][j] = f32x4_t{0.f, 0.f, 0.f, 0.f};

  const int nk = K >> 5;
  for (int kt = 0; kt < nk; ++kt) {
    const int k0 = kt * 32;
#pragma unroll
    for (int j = 0; j < 2; ++j) {
      const int rb = j * 64 + w * 16;
      const int r = rb + (l >> 2);
      const int c = (l & 3) * 8;
      gload_lds16(A + (size_t)(m0 + r) * K + k0 + c, &As[rb * 32]);
      gload_lds16(Bt + (size_t)(n0 + r) * K + k0 + c, &Bs[rb * 32]);
    }
    __syncthreads();
    bf16x8_t af[4], bfr[4];
#pragma unroll
    for (int i = 0; i < 4; ++i) {
      af[i] = *(const bf16x8_t*)&As[(wm * 64 + i * 16 + lr) * 32 + lg * 8];
      bfr[i] = *(const bf16x8_t*)&Bs[(wn * 64 + i * 16 + lr) * 32 + lg * 8];
    }
#pragma unroll
    for (int mf = 0; mf < 4; ++mf)
#pragma unroll
      for (int nf = 0; nf < 4; ++nf)
        acc[mf][nf] = mfma16(af[mf], bfr[nf], acc[mf][nf]);
    __syncthreads();
  }

  if constexpr (EPI == 0) {
#pragma unroll
    for (int mf = 0; mf < 4; ++mf)
#pragma unroll
      for (int r = 0; r < 4; ++r) {
        const int grow = m0 + wm * 64 + mf * 16 + 4 * lg + r;
#pragma unroll
        for (int nf = 0; nf < 4; ++nf) {
          const int gcol = n0 + wn * 64 + nf * 16 + lr;
          Cf[(size_t)grow * N + gcol] = acc[mf][nf][r];
        }
      }
  } else {
#pragma unroll
    for (int mf = 0; mf < 4; ++mf)
#pragma unroll
      for (int r = 0; r < 4; ++r) {
        const int grow = m0 + wm * 64 + mf * 16 + 4 * lg + r;
        const int b = grow >> 6, i = grow & 63;
#pragma unroll
        for (int nf = 0; nf < 4; ++nf) {
          const int gcol = n0 + wn * 64 + nf * 16 + lr;
          const int h = gcol >> 6, d = gcol & 63;
          C0[((size_t)((b * 16 + h) * 64 + i)) * 64 + d] = (bf16)acc[mf][nf][r];
        }
      }
  }
}

// ---------------- 256x256 8-phase GEMM for the kv projection ----------------
// A[M,K] * Bt[N,K]^T; K cols 0..1023 -> k[b,h,s,d]; cols 1024..2047 -> v^T[b,h,d,s].
// 8 waves (2M x 4N), BK=64, double-buffered swizzled LDS.
// Staging depths: B (L2-warm, 4MB) staged 1 tile ahead (ph0/ph1 -> nxt buf);
// A (HBM stream, 68MB) staged 2 tiles ahead (ph3 -> cur buf; safe: all A-cur
// ds_reads drained at ph2's lgkmcnt(0)+barrier). One vmcnt(4)/tile: drains
// A(kt+1)+B(kt+1), leaves A(kt+2) in flight.
__global__ __launch_bounds__(512, 2) void gemm256_kv(const bf16* __restrict__ A,
                                                     const bf16* __restrict__ Bt,
                                                     bf16* __restrict__ Kout,
                                                     bf16* __restrict__ Vout,
                                                     int M, int N, int K) {
  extern __shared__ char lds[];
  const int tid = threadIdx.x;
  const int w = tid >> 6, l = tid & 63;
  const int lr = l & 15, lg = l >> 4;
  const int wr = w >> 2, wc = w & 3;

  // XCD-aware bijective swizzle (nwg % 8 == 0 by construction)
  const int nwg = gridDim.x;
  const int cpx = nwg >> 3;
  const int swz = (blockIdx.x & 7) * cpx + (blockIdx.x >> 3);
  const int ntn = N >> 8;
  const int tm = swz / ntn, tn = swz % ntn;
  const int m0 = tm << 8, n0 = tn << 8;

  // stage one 128-row half (16 KB): 2 x global_load_lds(16B) per thread.
  // LDS dest linear; source col pre-swizzled so LDS content is XOR-swizzled.
  auto stage = [&](const bf16* __restrict__ G, int row0, int k0, char* base, int half) {
#pragma unroll
    for (int j = 0; j < 2; ++j) {
      const int r0 = half * 128 + (w * 2 + j) * 8;
      const int row = r0 + (l >> 3);
      const int col = ((l & 7) ^ (l >> 3)) * 8;
      gload_lds16(G + (size_t)(row0 + row) * K + k0 + col, base + r0 * 128);
    }
  };
  auto rdA = [&](char* base, int mf, int ks) -> bf16x8_t {
    const int row = wr * 128 + mf * 16 + lr;
    int byte = row * 128 + (ks * 32 + lg * 8) * 2;
    byte ^= (row & 7) << 4;
    return *(const bf16x8_t*)(base + byte);
  };
  auto rdB = [&](char* base, int nf, int ks) -> bf16x8_t {
    const int row = wc * 64 + nf * 16 + lr;
    int byte = row * 128 + (ks * 32 + lg * 8) * 2;
    byte ^= (row & 7) << 4;
    return *(const bf16x8_t*)(base + byte);
  };

  f32x4_t acc[8][4];
#pragma unroll
  for (int i = 0; i < 8; ++i)
#pragma unroll
    for (int j = 0; j < 4; ++j)
      acc[i][j] = f32x4_t{0.f, 0.f, 0.f, 0.f};

  const int NK = K >> 6;  // 16

  // prologue: A(0), B(0), A(1) — oldest-first so vmcnt(4) drains A(0)+B(0)
  stage(A, m0, 0, lds, 0);
  stage(A, m0, 0, lds, 1);
  stage(Bt, n0, 0, lds + 32768, 0);
  stage(Bt, n0, 0, lds + 32768, 1);
  stage(A, m0, 64, lds + 65536, 0);
  stage(A, m0, 64, lds + 65536, 1);
  asm volatile("s_waitcnt vmcnt(4)" ::: "memory");
  __builtin_amdgcn_s_barrier();

  bf16x8_t ra[4][2], rb[4][2];
  for (int kt = 0; kt < NK; ++kt) {
    const int cur = kt & 1, nxt = cur ^ 1;
    char* Ac = lds + cur * 65536;
    char* Bc = lds + 32768 + cur * 65536;
    char* Bn = lds + 32768 + nxt * 65536;
    const int k1 = (kt + 1) << 6, k2 = (kt + 2) << 6;

    // ---- phase 0: ds-read A mf0-3 + B nf0-1; stage B-h0(kt+1)
#pragma unroll
    for (int mf = 0; mf < 4; ++mf) { ra[mf][0] = rdA(Ac, mf, 0); ra[mf][1] = rdA(Ac, mf, 1); }
#pragma unroll
    for (int nf = 0; nf < 2; ++nf) { rb[nf][0] = rdB(Bc, nf, 0); rb[nf][1] = rdB(Bc, nf, 1); }
    if (kt + 1 < NK) stage(Bt, n0, k1, Bn, 0);
    asm volatile("s_waitcnt lgkmcnt(8)" ::: "memory");
    __builtin_amdgcn_s_barrier();
    asm volatile("s_waitcnt lgkmcnt(0)" ::: "memory");
    __builtin_amdgcn_sched_barrier(0);
    __builtin_amdgcn_s_setprio(1);
#pragma unroll
    for (int mf = 0; mf < 4; ++mf)
#pragma unroll
      for (int nf = 0; nf < 2; ++nf) {
        acc[mf][nf] = mfma16(ra[mf][0], rb[nf][0], acc[mf][nf]);
        acc[mf][nf] = mfma16(ra[mf][1], rb[nf][1], acc[mf][nf]);
      }
    __builtin_amdgcn_s_setprio(0);
    __builtin_amdgcn_sched_barrier(0);
    __builtin_amdgcn_s_barrier();

    // ---- phase 1: ds-read B nf2-3; stage B-h1(kt+1)
#pragma unroll
    for (int nf = 2; nf < 4; ++nf) { rb[nf][0] = rdB(Bc, nf, 0); rb[nf][1] = rdB(Bc, nf, 1); }
    if (kt + 1 < NK) stage(Bt, n0, k1, Bn, 1);
    __builtin_amdgcn_s_barrier();
    asm volatile("s_waitcnt lgkmcnt(0)" ::: "memory");
    __builtin_amdgcn_sched_barrier(0);
    __builtin_amdgcn_s_setprio(1);
#pragma unroll
    for (int mf = 0; mf < 4; ++mf)
#pragma unroll
      for (int nf = 2; nf < 4; ++nf) {
        acc[mf][nf] = mfma16(ra[mf][0], rb[nf][0], acc[mf][nf]);
        acc[mf][nf] = mfma16(ra[mf][1], rb[nf][1], acc[mf][nf]);
      }
    __builtin_amdgcn_s_setprio(0);
    __builtin_amdgcn_sched_barrier(0);
    __builtin_amdgcn_s_barrier();

    // ---- phase 2: ds-read A mf4-7 (drains all A-cur reads before ph3's A-stage)
#pragma unroll
    for (int mf = 0; mf < 4; ++mf) { ra[mf][0] = rdA(Ac, mf + 4, 0); ra[mf][1] = rdA(Ac, mf + 4, 1); }
    __builtin_amdgcn_s_barrier();
    asm volatile("s_waitcnt lgkmcnt(0)" ::: "memory");
    __builtin_amdgcn_sched_barrier(0);
    __builtin_amdgcn_s_setprio(1);
#pragma unroll
    for (int mf = 0; mf < 4; ++mf)
#pragma unroll
      for (int nf = 0; nf < 2; ++nf) {
        acc[mf + 4][nf] = mfma16(ra[mf][0], rb[nf][0], acc[mf + 4][nf]);
        acc[mf + 4][nf] = mfma16(ra[mf][1], rb[nf][1], acc[mf + 4][nf]);
      }
    __builtin_amdgcn_s_setprio(0);
    __builtin_amdgcn_sched_barrier(0);
    __builtin_amdgcn_s_barrier();

    // ---- phase 3: stage A(kt+2) into A-cur (safe after ph2 drain); MFMA mf4-7 x nf2-3
    if (kt + 2 < NK) { stage(A, m0, k2, Ac, 0); stage(A, m0, k2, Ac, 1); }
    __builtin_amdgcn_s_barrier();
    __builtin_amdgcn_sched_barrier(0);
    __builtin_amdgcn_s_setprio(1);
#pragma unroll
    for (int mf = 0; mf < 4; ++mf)
#pragma unroll
      for (int nf = 2; nf < 4; ++nf) {
        acc[mf + 4][nf] = mfma16(ra[mf][0], rb[nf][0], acc[mf + 4][nf]);
        acc[mf + 4][nf] = mfma16(ra[mf][1], rb[nf][1], acc[mf + 4][nf]);
      }
    __builtin_amdgcn_s_setprio(0);
    __builtin_amdgcn_sched_barrier(0);
    if (kt + 2 < NK)
      asm volatile("s_waitcnt vmcnt(4)" ::: "memory");
    else
      asm volatile("s_waitcnt vmcnt(0)" ::: "memory");
    __builtin_amdgcn_s_barrier();
  }

  // epilogue scatter
#pragma unroll
  for (int mf = 0; mf < 8; ++mf) {
    const int grow0 = m0 + wr * 128 + mf * 16 + 4 * lg;
#pragma unroll
    for (int nf = 0; nf < 4; ++nf) {
      const int gcol = n0 + wc * 64 + nf * 16 + lr;
      if (gcol < 1024) {  // K half: k[b,h,s,d]
        const int h = gcol >> 6, d = gcol & 63;
#pragma unroll
        for (int r = 0; r < 4; ++r) {
          const int grow = grow0 + r;
          const int bb = grow / 4160, s = grow % 4160;
          Kout[((size_t)((bb * 16 + h) * 4160 + s)) * 64 + d] = (bf16)acc[mf][nf][r];
        }
      } else {  // V half: v^T[b,h,d,s], pack 4 consecutive s
        const int c2 = gcol - 1024, h = c2 >> 6, d = c2 & 63;
        const int bb = grow0 / 4160, s0 = grow0 % 4160;
        ushort4 u;
        u.x = bfbits(acc[mf][nf][0]);
        u.y = bfbits(acc[mf][nf][1]);
        u.z = bfbits(acc[mf][nf][2]);
        u.w = bfbits(acc[mf][nf][3]);
        *(ushort4*)&Vout[((size_t)((bb * 16 + h) * 64 + d)) * 4160 + s0] = u;
      }
    }
  }
}

// ---------------- flash attention partials: 4 waves/WG, 13 kv-chunks ----------------
__global__ __launch_bounds__(256) void attn_part(const bf16* __restrict__ qb_,
                                                 const bf16* __restrict__ kb_,
                                                 const bf16* __restrict__ vb_,
                                                 float* __restrict__ ob,
                                                 float* __restrict__ mb,
                                                 float* __restrict__ lb) {
  const int c = blockIdx.x;   // 0..12
  const int bh = blockIdx.y;  // 0..127
  const int tid = threadIdx.x;
  const int wave = tid >> 6, l = tid & 63;
  const int lg = l >> 4, lr = l & 15;
  const int qr0 = wave * 16;

  const bf16* q = qb_ + ((size_t)bh * 64 + qr0) * 64;
  const bf16* Kp = kb_ + (size_t)bh * 4160 * 64;
  const bf16* Vt = vb_ + (size_t)bh * 64 * 4160;

  bf16x8_t qf[2];
#pragma unroll
  for (int kk = 0; kk < 2; ++kk)
    qf[kk] = *(const bf16x8_t*)(q + lr * 64 + kk * 32 + lg * 8);

  f32x4_t oacc[4];
  float m[4], lsum[4];
#pragma unroll
  for (int r = 0; r < 4; ++r) { m[r] = -1e30f; lsum[r] = 0.f; }
#pragma unroll
  for (int nf = 0; nf < 4; ++nf) oacc[nf] = f32x4_t{0.f, 0.f, 0.f, 0.f};

  __shared__ bf16 plds[4][16][72];
  bf16(*P)[72] = plds[wave];

  constexpr float inv = 1.0f / 64.0f;

  for (int kt = 0; kt < 5; ++kt) {
    const int key0 = c * 320 + kt * 64;
    f32x4_t sf[4];
#pragma unroll
    for (int nf = 0; nf < 4; ++nf) sf[nf] = f32x4_t{0.f, 0.f, 0.f, 0.f};
#pragma unroll
    for (int kk = 0; kk < 2; ++kk)
#pragma unroll
      for (int nf = 0; nf < 4; ++nf) {
        bf16x8_t kf = *(const bf16x8_t*)(Kp + (size_t)(key0 + nf * 16 + lr) * 64 + kk * 32 + lg * 8);
        sf[nf] = mfma16(qf[kk], kf, sf[nf]);
      }
    float corr[4];
#pragma unroll
    for (int r = 0; r < 4; ++r) {
      float t = fmaxf(fmaxf(sf[0][r], sf[1][r]), fmaxf(sf[2][r], sf[3][r])) * inv;
#pragma unroll
      for (int off = 1; off < 16; off <<= 1) t = fmaxf(t, __shfl_xor(t, off));
      const float mn = fmaxf(t, m[r]);
      corr[r] = __expf(m[r] - mn);
      m[r] = mn;
    }
    float rowsum[4] = {0.f, 0.f, 0.f, 0.f};
#pragma unroll
    for (int nf = 0; nf < 4; ++nf)
#pragma unroll
      for (int r = 0; r < 4; ++r) {
        const float p = __expf(sf[nf][r] * inv - m[r]);
        rowsum[r] += p;
        P[lg * 4 + r][nf * 16 + lr] = (bf16)p;
      }
#pragma unroll
    for (int r = 0; r < 4; ++r) {
      float t = rowsum[r];
#pragma unroll
      for (int off = 1; off < 16; off <<= 1) t += __shfl_xor(t, off);
      lsum[r] = lsum[r] * corr[r] + t;
    }
#pragma unroll
    for (int nf = 0; nf < 4; ++nf) {
      oacc[nf][0] *= corr[0];
      oacc[nf][1] *= corr[1];
      oacc[nf][2] *= corr[2];
      oacc[nf][3] *= corr[3];
    }
    __syncthreads();
#pragma unroll
    for (int kk = 0; kk < 2; ++kk) {
      bf16x8_t pf = *(const bf16x8_t*)&P[lr][kk * 32 + lg * 8];
#pragma unroll
      for (int nf = 0; nf < 4; ++nf) {
        bf16x8_t vf = *(const bf16x8_t*)(Vt + (size_t)(nf * 16 + lr) * 4160 + key0 + kk * 32 + lg * 8);
        oacc[nf] = mfma16(pf, vf, oacc[nf]);
      }
    }
    __syncthreads();
  }

  // write partials (no 1/l normalization here)
#pragma unroll
  for (int nf = 0; nf < 4; ++nf)
#pragma unroll
    for (int r = 0; r < 4; ++r) {
      const int i = qr0 + lg * 4 + r;
      ob[((size_t)((bh * 64 + i) * 13 + c)) * 64 + nf * 16 + lr] = oacc[nf][r];
    }
  if (lr == 0) {
#pragma unroll
    for (int r = 0; r < 4; ++r) {
      const int i = qr0 + lg * 4 + r;
      mb[(bh * 64 + i) * 13 + c] = m[r];
      lb[(bh * 64 + i) * 13 + c] = lsum[r];
    }
  }
}

// ---------------- merge partials -> aout[b*64+i][h*64+d] bf16 ----------------
__global__ __launch_bounds__(256) void attn_merge(const float* __restrict__ ob,
                                                  const float* __restrict__ mb,
                                                  const float* __restrict__ lb,
                                                  bf16* __restrict__ aout) {
  const int j = blockIdx.x * 4 + (threadIdx.x >> 6);  // row 0..8191
  const int l = threadIdx.x & 63;
  float mv[13];
  float mx = -1e30f;
#pragma unroll
  for (int cc = 0; cc < 13; ++cc) { mv[cc] = mb[j * 13 + cc]; mx = fmaxf(mx, mv[cc]); }
  float L = 0.f, o = 0.f;
#pragma unroll
  for (int cc = 0; cc < 13; ++cc) {
    const float wgt = __expf(mv[cc] - mx);
    L += lb[j * 13 + cc] * wgt;
    o += wgt * ob[((size_t)(j * 13 + cc)) * 64 + l];
  }
  const int bh = j >> 6, i = j & 63, b = bh >> 4, h = bh & 15;
  aout[((size_t)(b * 64 + i)) * 1024 + h * 64 + l] = (bf16)(o / L);
}

// ---------------- launch ----------------
extern "C" void kernel_launch(void* const* d_in, const int* in_sizes, int n_in,
                              void* d_out, int out_size, void* d_ws, size_t ws_size,
                              hipStream_t stream) {
  (void)in_sizes; (void)n_in; (void)out_size; (void)ws_size;
  const float* x   = (const float*)d_in[0];
  const float* lat = (const float*)d_in[1];
  const float* g1  = (const float*)d_in[2];
  const float* b1  = (const float*)d_in[3];
  const float* g2  = (const float*)d_in[4];
  const float* b2  = (const float*)d_in[5];
  const float* Wq  = (const float*)d_in[6];
  const float* Wkv = (const float*)d_in[7];
  const float* Wo  = (const float*)d_in[8];
  float* out = (float*)d_out;

  char* ws = (char*)d_ws;
  size_t off = 0;
  auto alloc = [&](size_t bytes) {
    void* p = ws + off;
    off += (bytes + 255) & ~(size_t)255;
    return p;
  };
  bf16* kv_in = (bf16*)alloc(8ull * 4160 * 1024 * 2);     // concat(xn, ln) rows
  bf16* Wkv_t = (bf16*)alloc(2048ull * 1024 * 2);
  bf16* Wq_t  = (bf16*)alloc(1024ull * 1024 * 2);
  bf16* Wo_t  = (bf16*)alloc(1024ull * 1024 * 2);
  bf16* lnq   = (bf16*)alloc(512ull * 1024 * 2);
  bf16* qbuf  = (bf16*)alloc(512ull * 1024 * 2);          // [b,h,i,d]
  bf16* kbuf  = (bf16*)alloc(8ull * 16 * 4160 * 64 * 2);  // [b,h,s,d]
  bf16* vtbuf = (bf16*)alloc(8ull * 16 * 4160 * 64 * 2);  // [b,h,d,s]
  bf16* aout  = (bf16*)alloc(512ull * 1024 * 2);          // [b*64+i, h*64+d]

  // attention partials aliased into kv_in (dead after gemm256_kv; rewritten by LN each call)
  float* obuf = (float*)kv_in;            // 8192 * 13 * 64 f32
  float* mbuf = obuf + 8192ull * 13 * 64; // 8192 * 13
  float* lbuf = mbuf + 8192ull * 13;

  (void)hipFuncSetAttribute(reinterpret_cast<const void*>(gemm256_kv),
                            hipFuncAttributeMaxDynamicSharedMemorySize, 131072);

  dim3 tb(32, 8);
  transpose_cvt<<<dim3(1024 / 32, 1024 / 32), tb, 0, stream>>>(Wq, Wq_t, 1024, 1024);
  transpose_cvt<<<dim3(2048 / 32, 1024 / 32), tb, 0, stream>>>(Wkv, Wkv_t, 1024, 2048);
  transpose_cvt<<<dim3(1024 / 32, 1024 / 32), tb, 0, stream>>>(Wo, Wo_t, 1024, 1024);

  ln_kernel<false><<<32768, 256, 0, stream>>>(x, g1, b1, kv_in, nullptr, 4096, 0);
  ln_kernel<true><<<512, 256, 0, stream>>>(lat, g2, b2, kv_in, lnq, 64, 4096);

  gemm_bt<1><<<dim3(1024 / 128, 512 / 128), 256, 0, stream>>>(lnq, Wq_t, nullptr, qbuf, 512, 1024, 1024);
  gemm256_kv<<<1040, 512, 131072, stream>>>(kv_in, Wkv_t, kbuf, vtbuf, 33280, 2048, 1024);

  attn_part<<<dim3(13, 128), 256, 0, stream>>>(qbuf, kbuf, vtbuf, obuf, mbuf, lbuf);
  attn_merge<<<2048, 256, 0, stream>>>(obuf, mbuf, lbuf, aout);

  gemm_bt<0><<<dim3(1024 / 128, 512 / 128), 256, 0, stream>>>(aout, Wo_t, out, nullptr, 512, 1024, 1024);
}

// Round 5
// 345.695 us; speedup vs baseline: 1.0687x; 1.0687x over previous
//
#include <hip/hip_runtime.h>

typedef __bf16 bf16;
typedef bf16 bf16x4_t __attribute__((ext_vector_type(4)));
typedef bf16 bf16x8_t __attribute__((ext_vector_type(8)));
typedef float f32x4_t __attribute__((ext_vector_type(4)));

#define DI __device__ __forceinline__

DI void gload_lds16(const void* g, void* l) {
  __builtin_amdgcn_global_load_lds((const __attribute__((address_space(1))) void*)g,
                                   (__attribute__((address_space(3))) void*)l, 16, 0, 0);
}

DI f32x4_t mfma16(bf16x8_t a, bf16x8_t b, f32x4_t c) {
  return __builtin_amdgcn_mfma_f32_16x16x32_bf16(a, b, c, 0, 0, 0);
}

DI unsigned short bfbits(float f) {
  bf16 h = (bf16)f;
  return __builtin_bit_cast(unsigned short, h);
}

// ---------------- LayerNorm (f32 in -> bf16 out), one row per block ----------------
template<bool DUAL>
__global__ __launch_bounds__(256) void ln_kernel(const float* __restrict__ in,
                                                 const float* __restrict__ gamma,
                                                 const float* __restrict__ beta,
                                                 bf16* __restrict__ out1,
                                                 bf16* __restrict__ out2,
                                                 int rpb, int base) {
  const int row = blockIdx.x;
  const int t = threadIdx.x;
  const float4 v = ((const float4*)(in + (size_t)row * 1024))[t];
  float s = v.x + v.y + v.z + v.w;
  float q = v.x * v.x + v.y * v.y + v.z * v.z + v.w * v.w;
#pragma unroll
  for (int off = 1; off < 64; off <<= 1) {
    s += __shfl_xor(s, off);
    q += __shfl_xor(q, off);
  }
  __shared__ float red[8];
  const int w = t >> 6;
  if ((t & 63) == 0) { red[w] = s; red[w + 4] = q; }
  __syncthreads();
  s = red[0] + red[1] + red[2] + red[3];
  q = red[4] + red[5] + red[6] + red[7];
  const float mu = s * (1.f / 1024.f);
  const float var = q * (1.f / 1024.f) - mu * mu;
  const float rs = rsqrtf(var + 1e-5f);
  const float4 gv = ((const float4*)gamma)[t];
  const float4 bv = ((const float4*)beta)[t];
  bf16x4_t o;
  o[0] = (bf16)((v.x - mu) * rs * gv.x + bv.x);
  o[1] = (bf16)((v.y - mu) * rs * gv.y + bv.y);
  o[2] = (bf16)((v.z - mu) * rs * gv.z + bv.z);
  o[3] = (bf16)((v.w - mu) * rs * gv.w + bv.w);
  const int b = row / rpb, r2 = row % rpb;
  *(bf16x4_t*)(out1 + ((size_t)b * 4160 + base + r2) * 1024 + t * 4) = o;
  if constexpr (DUAL) {
    *(bf16x4_t*)(out2 + (size_t)row * 1024 + t * 4) = o;
  }
}

// ---------------- transpose + cast: W[R][C] f32 -> Wt[C][R] bf16 ----------------
__global__ __launch_bounds__(256) void transpose_cvt(const float* __restrict__ W,
                                                     bf16* __restrict__ Wt, int R, int C) {
  __shared__ float tile[32][33];
  const int tx = threadIdx.x, ty = threadIdx.y;
  const int c0 = blockIdx.x * 32, r0 = blockIdx.y * 32;
#pragma unroll
  for (int j = 0; j < 4; ++j)
    tile[ty + j * 8][tx] = W[(size_t)(r0 + ty + j * 8) * C + c0 + tx];
  __syncthreads();
#pragma unroll
  for (int j = 0; j < 4; ++j)
    Wt[(size_t)(c0 + ty + j * 8) * R + r0 + tx] = (bf16)tile[tx][ty + j * 8];
}

// ---------------- small GEMM (128x128 tile): C = A * Bt^T ----------------
// EPI 0: f32 row-major out. EPI 1: q scatter to [b,h,i,d].
template<int EPI>
__global__ __launch_bounds__(256) void gemm_bt(const bf16* __restrict__ A,
                                               const bf16* __restrict__ Bt,
                                               float* __restrict__ Cf,
                                               bf16* __restrict__ C0,
                                               int M, int N, int K) {
  __shared__ bf16 As[128 * 32];
  __shared__ bf16 Bs[128 * 32];
  const int tid = threadIdx.x;
  const int w = tid >> 6, l = tid & 63;
  const int lg = l >> 4, lr = l & 15;
  const int m0 = blockIdx.y * 128, n0 = blockIdx.x * 128;
  const int wm = w >> 1, wn = w & 1;

  f32x4_t acc[4][4];
#pragma unroll
  for (int i = 0; i < 4; ++i)
#pragma unroll
    for (int j = 0; j < 4; ++j)
      acc[i][j] = f32x4_t{0.f, 0.f, 0.f, 0.f};

  const int nk = K >> 5;
  for (int kt = 0; kt < nk; ++kt) {
    const int k0 = kt * 32;
#pragma unroll
    for (int j = 0; j < 2; ++j) {
      const int rb = j * 64 + w * 16;
      const int r = rb + (l >> 2);
      const int c = (l & 3) * 8;
      gload_lds16(A + (size_t)(m0 + r) * K + k0 + c, &As[rb * 32]);
      gload_lds16(Bt + (size_t)(n0 + r) * K + k0 + c, &Bs[rb * 32]);
    }
    __syncthreads();
    bf16x8_t af[4], bfr[4];
#pragma unroll
    for (int i = 0; i < 4; ++i) {
      af[i] = *(const bf16x8_t*)&As[(wm * 64 + i * 16 + lr) * 32 + lg * 8];
      bfr[i] = *(const bf16x8_t*)&Bs[(wn * 64 + i * 16 + lr) * 32 + lg * 8];
    }
#pragma unroll
    for (int mf = 0; mf < 4; ++mf)
#pragma unroll
      for (int nf = 0; nf < 4; ++nf)
        acc[mf][nf] = mfma16(af[mf], bfr[nf], acc[mf][nf]);
    __syncthreads();
  }

  if constexpr (EPI == 0) {
#pragma unroll
    for (int mf = 0; mf < 4; ++mf)
#pragma unroll
      for (int r = 0; r < 4; ++r) {
        const int grow = m0 + wm * 64 + mf * 16 + 4 * lg + r;
#pragma unroll
        for (int nf = 0; nf < 4; ++nf) {
          const int gcol = n0 + wn * 64 + nf * 16 + lr;
          Cf[(size_t)grow * N + gcol] = acc[mf][nf][r];
        }
      }
  } else {
#pragma unroll
    for (int mf = 0; mf < 4; ++mf)
#pragma unroll
      for (int r = 0; r < 4; ++r) {
        const int grow = m0 + wm * 64 + mf * 16 + 4 * lg + r;
        const int b = grow >> 6, i = grow & 63;
#pragma unroll
        for (int nf = 0; nf < 4; ++nf) {
          const int gcol = n0 + wn * 64 + nf * 16 + lr;
          const int h = gcol >> 6, d = gcol & 63;
          C0[((size_t)((b * 16 + h) * 64 + i)) * 64 + d] = (bf16)acc[mf][nf][r];
        }
      }
  }
}

// ---------------- 256x256 4-phase GEMM for the kv projection ----------------
// A[M,K] * Bt[N,K]^T; K cols 0..1023 -> k[b,h,s,d]; cols 1024..2047 -> v^T[b,h,d,s].
// 8 waves (2M x 4N), BK=64, double-buffered swizzled LDS.
// ONE barrier per phase: {ds_reads; stage; lgkmcnt(0); barrier; MFMA}.
// After each barrier all prior LDS reads are globally complete, so the next
// phase's stage into a fully-read region is safe, and each wave's next-phase
// read issue overlaps other waves' MFMA. B staged 1 tile ahead (ph0/ph1 -> nxt),
// A staged 2 tiles ahead (ph3 -> cur, safe after ph2's global drain).
// vmcnt(4) once per tile: drains A(kt+1)+B(kt+1), leaves A(kt+2) in flight.
__global__ __launch_bounds__(512, 2) void gemm256_kv(const bf16* __restrict__ A,
                                                     const bf16* __restrict__ Bt,
                                                     bf16* __restrict__ Kout,
                                                     bf16* __restrict__ Vout,
                                                     int M, int N, int K) {
  extern __shared__ char lds[];
  const int tid = threadIdx.x;
  const int w = tid >> 6, l = tid & 63;
  const int lr = l & 15, lg = l >> 4;
  const int wr = w >> 2, wc = w & 3;

  // XCD-aware bijective swizzle (nwg % 8 == 0 by construction)
  const int nwg = gridDim.x;
  const int cpx = nwg >> 3;
  const int swz = (blockIdx.x & 7) * cpx + (blockIdx.x >> 3);
  const int ntn = N >> 8;
  const int tm = swz / ntn, tn = swz % ntn;
  const int m0 = tm << 8, n0 = tn << 8;

  // stage one 128-row half (16 KB): 2 x global_load_lds(16B) per thread.
  // LDS dest linear; source col pre-swizzled so LDS content is XOR-swizzled.
  auto stage = [&](const bf16* __restrict__ G, int row0, int k0, char* base, int half) {
#pragma unroll
    for (int j = 0; j < 2; ++j) {
      const int r0 = half * 128 + (w * 2 + j) * 8;
      const int row = r0 + (l >> 3);
      const int col = ((l & 7) ^ (l >> 3)) * 8;
      gload_lds16(G + (size_t)(row0 + row) * K + k0 + col, base + r0 * 128);
    }
  };
  auto rdA = [&](char* base, int mf, int ks) -> bf16x8_t {
    const int row = wr * 128 + mf * 16 + lr;
    int byte = row * 128 + (ks * 32 + lg * 8) * 2;
    byte ^= (row & 7) << 4;
    return *(const bf16x8_t*)(base + byte);
  };
  auto rdB = [&](char* base, int nf, int ks) -> bf16x8_t {
    const int row = wc * 64 + nf * 16 + lr;
    int byte = row * 128 + (ks * 32 + lg * 8) * 2;
    byte ^= (row & 7) << 4;
    return *(const bf16x8_t*)(base + byte);
  };

  f32x4_t acc[8][4];
#pragma unroll
  for (int i = 0; i < 8; ++i)
#pragma unroll
    for (int j = 0; j < 4; ++j)
      acc[i][j] = f32x4_t{0.f, 0.f, 0.f, 0.f};

  const int NK = K >> 6;  // 16

  // prologue: A(0), B(0), A(1) — oldest-first so vmcnt(4) drains A(0)+B(0)
  stage(A, m0, 0, lds, 0);
  stage(A, m0, 0, lds, 1);
  stage(Bt, n0, 0, lds + 32768, 0);
  stage(Bt, n0, 0, lds + 32768, 1);
  stage(A, m0, 64, lds + 65536, 0);
  stage(A, m0, 64, lds + 65536, 1);
  asm volatile("s_waitcnt vmcnt(4)" ::: "memory");
  __builtin_amdgcn_s_barrier();

  bf16x8_t ra[4][2], rb[4][2];
  for (int kt = 0; kt < NK; ++kt) {
    const int cur = kt & 1, nxt = cur ^ 1;
    char* Ac = lds + cur * 65536;
    char* Bc = lds + 32768 + cur * 65536;
    char* Bn = lds + 32768 + nxt * 65536;
    const int k1 = (kt + 1) << 6, k2 = (kt + 2) << 6;

    // ---- phase 0: reads A mf0-3 + B nf0-1; stage B-h0(kt+1); 1 barrier; MFMA
#pragma unroll
    for (int mf = 0; mf < 4; ++mf) { ra[mf][0] = rdA(Ac, mf, 0); ra[mf][1] = rdA(Ac, mf, 1); }
#pragma unroll
    for (int nf = 0; nf < 2; ++nf) { rb[nf][0] = rdB(Bc, nf, 0); rb[nf][1] = rdB(Bc, nf, 1); }
    if (kt + 1 < NK) stage(Bt, n0, k1, Bn, 0);
    asm volatile("s_waitcnt lgkmcnt(0)" ::: "memory");
    __builtin_amdgcn_sched_barrier(0);
    __builtin_amdgcn_s_barrier();
    __builtin_amdgcn_s_setprio(1);
#pragma unroll
    for (int mf = 0; mf < 4; ++mf)
#pragma unroll
      for (int nf = 0; nf < 2; ++nf) {
        acc[mf][nf] = mfma16(ra[mf][0], rb[nf][0], acc[mf][nf]);
        acc[mf][nf] = mfma16(ra[mf][1], rb[nf][1], acc[mf][nf]);
      }
    __builtin_amdgcn_s_setprio(0);

    // ---- phase 1: reads B nf2-3; stage B-h1(kt+1); 1 barrier; MFMA
#pragma unroll
    for (int nf = 2; nf < 4; ++nf) { rb[nf][0] = rdB(Bc, nf, 0); rb[nf][1] = rdB(Bc, nf, 1); }
    if (kt + 1 < NK) stage(Bt, n0, k1, Bn, 1);
    asm volatile("s_waitcnt lgkmcnt(0)" ::: "memory");
    __builtin_amdgcn_sched_barrier(0);
    __builtin_amdgcn_s_barrier();
    __builtin_amdgcn_s_setprio(1);
#pragma unroll
    for (int mf = 0; mf < 4; ++mf)
#pragma unroll
      for (int nf = 2; nf < 4; ++nf) {
        acc[mf][nf] = mfma16(ra[mf][0], rb[nf][0], acc[mf][nf]);
        acc[mf][nf] = mfma16(ra[mf][1], rb[nf][1], acc[mf][nf]);
      }
    __builtin_amdgcn_s_setprio(0);

    // ---- phase 2: reads A mf4-7; 1 barrier; MFMA (all A-cur reads drained here)
#pragma unroll
    for (int mf = 0; mf < 4; ++mf) { ra[mf][0] = rdA(Ac, mf + 4, 0); ra[mf][1] = rdA(Ac, mf + 4, 1); }
    asm volatile("s_waitcnt lgkmcnt(0)" ::: "memory");
    __builtin_amdgcn_sched_barrier(0);
    __builtin_amdgcn_s_barrier();
    __builtin_amdgcn_s_setprio(1);
#pragma unroll
    for (int mf = 0; mf < 4; ++mf)
#pragma unroll
      for (int nf = 0; nf < 2; ++nf) {
        acc[mf + 4][nf] = mfma16(ra[mf][0], rb[nf][0], acc[mf + 4][nf]);
        acc[mf + 4][nf] = mfma16(ra[mf][1], rb[nf][1], acc[mf + 4][nf]);
      }
    __builtin_amdgcn_s_setprio(0);

    // ---- phase 3: stage A(kt+2) into A-cur (safe after ph2 barrier); vmcnt; barrier; MFMA
    if (kt + 2 < NK) { stage(A, m0, k2, Ac, 0); stage(A, m0, k2, Ac, 1); }
    if (kt + 2 < NK)
      asm volatile("s_waitcnt vmcnt(4)" ::: "memory");
    else
      asm volatile("s_waitcnt vmcnt(0)" ::: "memory");
    __builtin_amdgcn_sched_barrier(0);
    __builtin_amdgcn_s_barrier();
    __builtin_amdgcn_s_setprio(1);
#pragma unroll
    for (int mf = 0; mf < 4; ++mf)
#pragma unroll
      for (int nf = 2; nf < 4; ++nf) {
        acc[mf + 4][nf] = mfma16(ra[mf][0], rb[nf][0], acc[mf + 4][nf]);
        acc[mf + 4][nf] = mfma16(ra[mf][1], rb[nf][1], acc[mf + 4][nf]);
      }
    __builtin_amdgcn_s_setprio(0);
  }

  // epilogue scatter
#pragma unroll
  for (int mf = 0; mf < 8; ++mf) {
    const int grow0 = m0 + wr * 128 + mf * 16 + 4 * lg;
#pragma unroll
    for (int nf = 0; nf < 4; ++nf) {
      const int gcol = n0 + wc * 64 + nf * 16 + lr;
      if (gcol < 1024) {  // K half: k[b,h,s,d]
        const int h = gcol >> 6, d = gcol & 63;
#pragma unroll
        for (int r = 0; r < 4; ++r) {
          const int grow = grow0 + r;
          const int bb = grow / 4160, s = grow % 4160;
          Kout[((size_t)((bb * 16 + h) * 4160 + s)) * 64 + d] = (bf16)acc[mf][nf][r];
        }
      } else {  // V half: v^T[b,h,d,s], pack 4 consecutive s
        const int c2 = gcol - 1024, h = c2 >> 6, d = c2 & 63;
        const int bb = grow0 / 4160, s0 = grow0 % 4160;
        ushort4 u;
        u.x = bfbits(acc[mf][nf][0]);
        u.y = bfbits(acc[mf][nf][1]);
        u.z = bfbits(acc[mf][nf][2]);
        u.w = bfbits(acc[mf][nf][3]);
        *(ushort4*)&Vout[((size_t)((bb * 16 + h) * 64 + d)) * 4160 + s0] = u;
      }
    }
  }
}

// ---------------- flash attention partials: 4 waves/WG, 5 kv-chunks ----------------
__global__ __launch_bounds__(256) void attn_part(const bf16* __restrict__ qb_,
                                                 const bf16* __restrict__ kb_,
                                                 const bf16* __restrict__ vb_,
                                                 float* __restrict__ ob,
                                                 float* __restrict__ mb,
                                                 float* __restrict__ lb) {
  const int c = blockIdx.x;   // 0..4
  const int bh = blockIdx.y;  // 0..127
  const int tid = threadIdx.x;
  const int wave = tid >> 6, l = tid & 63;
  const int lg = l >> 4, lr = l & 15;
  const int qr0 = wave * 16;

  const bf16* q = qb_ + ((size_t)bh * 64 + qr0) * 64;
  const bf16* Kp = kb_ + (size_t)bh * 4160 * 64;
  const bf16* Vt = vb_ + (size_t)bh * 64 * 4160;

  bf16x8_t qf[2];
#pragma unroll
  for (int kk = 0; kk < 2; ++kk)
    qf[kk] = *(const bf16x8_t*)(q + lr * 64 + kk * 32 + lg * 8);

  f32x4_t oacc[4];
  float m[4], lsum[4];
#pragma unroll
  for (int r = 0; r < 4; ++r) { m[r] = -1e30f; lsum[r] = 0.f; }
#pragma unroll
  for (int nf = 0; nf < 4; ++nf) oacc[nf] = f32x4_t{0.f, 0.f, 0.f, 0.f};

  __shared__ bf16 plds[4][16][72];
  bf16(*P)[72] = plds[wave];

  constexpr float inv = 1.0f / 64.0f;

  for (int kt = 0; kt < 13; ++kt) {
    const int key0 = c * 832 + kt * 64;
    f32x4_t sf[4];
#pragma unroll
    for (int nf = 0; nf < 4; ++nf) sf[nf] = f32x4_t{0.f, 0.f, 0.f, 0.f};
#pragma unroll
    for (int kk = 0; kk < 2; ++kk)
#pragma unroll
      for (int nf = 0; nf < 4; ++nf) {
        bf16x8_t kf = *(const bf16x8_t*)(Kp + (size_t)(key0 + nf * 16 + lr) * 64 + kk * 32 + lg * 8);
        sf[nf] = mfma16(qf[kk], kf, sf[nf]);
      }
    float corr[4];
#pragma unroll
    for (int r = 0; r < 4; ++r) {
      float t = fmaxf(fmaxf(sf[0][r], sf[1][r]), fmaxf(sf[2][r], sf[3][r])) * inv;
#pragma unroll
      for (int off = 1; off < 16; off <<= 1) t = fmaxf(t, __shfl_xor(t, off));
      const float mn = fmaxf(t, m[r]);
      corr[r] = __expf(m[r] - mn);
      m[r] = mn;
    }
    float rowsum[4] = {0.f, 0.f, 0.f, 0.f};
#pragma unroll
    for (int nf = 0; nf < 4; ++nf)
#pragma unroll
      for (int r = 0; r < 4; ++r) {
        const float p = __expf(sf[nf][r] * inv - m[r]);
        rowsum[r] += p;
        P[lg * 4 + r][nf * 16 + lr] = (bf16)p;
      }
#pragma unroll
    for (int r = 0; r < 4; ++r) {
      float t = rowsum[r];
#pragma unroll
      for (int off = 1; off < 16; off <<= 1) t += __shfl_xor(t, off);
      lsum[r] = lsum[r] * corr[r] + t;
    }
#pragma unroll
    for (int nf = 0; nf < 4; ++nf) {
      oacc[nf][0] *= corr[0];
      oacc[nf][1] *= corr[1];
      oacc[nf][2] *= corr[2];
      oacc[nf][3] *= corr[3];
    }
    __syncthreads();
#pragma unroll
    for (int kk = 0; kk < 2; ++kk) {
      bf16x8_t pf = *(const bf16x8_t*)&P[lr][kk * 32 + lg * 8];
#pragma unroll
      for (int nf = 0; nf < 4; ++nf) {
        bf16x8_t vf = *(const bf16x8_t*)(Vt + (size_t)(nf * 16 + lr) * 4160 + key0 + kk * 32 + lg * 8);
        oacc[nf] = mfma16(pf, vf, oacc[nf]);
      }
    }
    __syncthreads();
  }

  // write partials (no 1/l normalization here)
#pragma unroll
  for (int nf = 0; nf < 4; ++nf)
#pragma unroll
    for (int r = 0; r < 4; ++r) {
      const int i = qr0 + lg * 4 + r;
      ob[((size_t)((bh * 64 + i) * 5 + c)) * 64 + nf * 16 + lr] = oacc[nf][r];
    }
  if (lr == 0) {
#pragma unroll
    for (int r = 0; r < 4; ++r) {
      const int i = qr0 + lg * 4 + r;
      mb[(bh * 64 + i) * 5 + c] = m[r];
      lb[(bh * 64 + i) * 5 + c] = lsum[r];
    }
  }
}

// ---------------- merge partials -> aout[b*64+i][h*64+d] bf16 ----------------
__global__ __launch_bounds__(256) void attn_merge(const float* __restrict__ ob,
                                                  const float* __restrict__ mb,
                                                  const float* __restrict__ lb,
                                                  bf16* __restrict__ aout) {
  const int j = blockIdx.x * 4 + (threadIdx.x >> 6);  // row 0..8191
  const int l = threadIdx.x & 63;
  float mv[5];
  float mx = -1e30f;
#pragma unroll
  for (int cc = 0; cc < 5; ++cc) { mv[cc] = mb[j * 5 + cc]; mx = fmaxf(mx, mv[cc]); }
  float L = 0.f, o = 0.f;
#pragma unroll
  for (int cc = 0; cc < 5; ++cc) {
    const float wgt = __expf(mv[cc] - mx);
    L += lb[j * 5 + cc] * wgt;
    o += wgt * ob[((size_t)(j * 5 + cc)) * 64 + l];
  }
  const int bh = j >> 6, i = j & 63, b = bh >> 4, h = bh & 15;
  aout[((size_t)(b * 64 + i)) * 1024 + h * 64 + l] = (bf16)(o / L);
}

// ---------------- launch ----------------
extern "C" void kernel_launch(void* const* d_in, const int* in_sizes, int n_in,
                              void* d_out, int out_size, void* d_ws, size_t ws_size,
                              hipStream_t stream) {
  (void)in_sizes; (void)n_in; (void)out_size; (void)ws_size;
  const float* x   = (const float*)d_in[0];
  const float* lat = (const float*)d_in[1];
  const float* g1  = (const float*)d_in[2];
  const float* b1  = (const float*)d_in[3];
  const float* g2  = (const float*)d_in[4];
  const float* b2  = (const float*)d_in[5];
  const float* Wq  = (const float*)d_in[6];
  const float* Wkv = (const float*)d_in[7];
  const float* Wo  = (const float*)d_in[8];
  float* out = (float*)d_out;

  char* ws = (char*)d_ws;
  size_t off = 0;
  auto alloc = [&](size_t bytes) {
    void* p = ws + off;
    off += (bytes + 255) & ~(size_t)255;
    return p;
  };
  bf16* kv_in = (bf16*)alloc(8ull * 4160 * 1024 * 2);     // concat(xn, ln) rows
  bf16* Wkv_t = (bf16*)alloc(2048ull * 1024 * 2);
  bf16* Wq_t  = (bf16*)alloc(1024ull * 1024 * 2);
  bf16* Wo_t  = (bf16*)alloc(1024ull * 1024 * 2);
  bf16* lnq   = (bf16*)alloc(512ull * 1024 * 2);
  bf16* qbuf  = (bf16*)alloc(512ull * 1024 * 2);          // [b,h,i,d]
  bf16* kbuf  = (bf16*)alloc(8ull * 16 * 4160 * 64 * 2);  // [b,h,s,d]
  bf16* vtbuf = (bf16*)alloc(8ull * 16 * 4160 * 64 * 2);  // [b,h,d,s]
  bf16* aout  = (bf16*)alloc(512ull * 1024 * 2);          // [b*64+i, h*64+d]

  // attention partials aliased into kv_in (dead after gemm256_kv; rewritten by LN each call)
  float* obuf = (float*)kv_in;           // 8192 * 5 * 64 f32
  float* mbuf = obuf + 8192ull * 5 * 64; // 8192 * 5
  float* lbuf = mbuf + 8192ull * 5;

  (void)hipFuncSetAttribute(reinterpret_cast<const void*>(gemm256_kv),
                            hipFuncAttributeMaxDynamicSharedMemorySize, 131072);

  dim3 tb(32, 8);
  transpose_cvt<<<dim3(1024 / 32, 1024 / 32), tb, 0, stream>>>(Wq, Wq_t, 1024, 1024);
  transpose_cvt<<<dim3(2048 / 32, 1024 / 32), tb, 0, stream>>>(Wkv, Wkv_t, 1024, 2048);
  transpose_cvt<<<dim3(1024 / 32, 1024 / 32), tb, 0, stream>>>(Wo, Wo_t, 1024, 1024);

  ln_kernel<false><<<32768, 256, 0, stream>>>(x, g1, b1, kv_in, nullptr, 4096, 0);
  ln_kernel<true><<<512, 256, 0, stream>>>(lat, g2, b2, kv_in, lnq, 64, 4096);

  gemm_bt<1><<<dim3(1024 / 128, 512 / 128), 256, 0, stream>>>(lnq, Wq_t, nullptr, qbuf, 512, 1024, 1024);
  gemm256_kv<<<1040, 512, 131072, stream>>>(kv_in, Wkv_t, kbuf, vtbuf, 33280, 2048, 1024);

  attn_part<<<dim3(5, 128), 256, 0, stream>>>(qbuf, kbuf, vtbuf, obuf, mbuf, lbuf);
  attn_merge<<<2048, 256, 0, stream>>>(obuf, mbuf, lbuf, aout);

  gemm_bt<0><<<dim3(1024 / 128, 512 / 128), 256, 0, stream>>>(aout, Wo_t, out, nullptr, 512, 1024, 1024);
}

// Round 6
// 304.478 us; speedup vs baseline: 1.2134x; 1.1354x over previous
//
#include <hip/hip_runtime.h>

typedef __bf16 bf16;
typedef bf16 bf16x4_t __attribute__((ext_vector_type(4)));
typedef bf16 bf16x8_t __attribute__((ext_vector_type(8)));
typedef float f32x4_t __attribute__((ext_vector_type(4)));

#define DI __device__ __forceinline__

DI void gload_lds16(const void* g, void* l) {
  __builtin_amdgcn_global_load_lds((const __attribute__((address_space(1))) void*)g,
                                   (__attribute__((address_space(3))) void*)l, 16, 0, 0);
}

DI f32x4_t mfma16(bf16x8_t a, bf16x8_t b, f32x4_t c) {
  return __builtin_amdgcn_mfma_f32_16x16x32_bf16(a, b, c, 0, 0, 0);
}

DI unsigned short bfbits(float f) {
  bf16 h = (bf16)f;
  return __builtin_bit_cast(unsigned short, h);
}

// ---------------- fused LayerNorm (x rows then latent rows), one row per block ----------------
__global__ __launch_bounds__(256) void ln_all(const float* __restrict__ x,
                                              const float* __restrict__ lat,
                                              const float* __restrict__ g1,
                                              const float* __restrict__ b1,
                                              const float* __restrict__ g2,
                                              const float* __restrict__ b2,
                                              bf16* __restrict__ kv_in,
                                              bf16* __restrict__ lnq) {
  const int row = blockIdx.x;
  const int t = threadIdx.x;
  const float* in;
  const float* gamma;
  const float* beta;
  size_t orow;
  bool dual;
  int lrow = 0;
  if (row < 32768) {
    in = x + (size_t)row * 1024;
    gamma = g1; beta = b1;
    const int b = row >> 12, r2 = row & 4095;
    orow = (size_t)b * 4160 + r2;
    dual = false;
  } else {
    const int r = row - 32768;
    in = lat + (size_t)r * 1024;
    gamma = g2; beta = b2;
    const int b = r >> 6, r2 = r & 63;
    orow = (size_t)b * 4160 + 4096 + r2;
    dual = true;
    lrow = r;
  }
  const float4 v = ((const float4*)in)[t];
  float s = v.x + v.y + v.z + v.w;
  float q = v.x * v.x + v.y * v.y + v.z * v.z + v.w * v.w;
#pragma unroll
  for (int off = 1; off < 64; off <<= 1) {
    s += __shfl_xor(s, off);
    q += __shfl_xor(q, off);
  }
  __shared__ float red[8];
  const int w = t >> 6;
  if ((t & 63) == 0) { red[w] = s; red[w + 4] = q; }
  __syncthreads();
  s = red[0] + red[1] + red[2] + red[3];
  q = red[4] + red[5] + red[6] + red[7];
  const float mu = s * (1.f / 1024.f);
  const float var = q * (1.f / 1024.f) - mu * mu;
  const float rs = rsqrtf(var + 1e-5f);
  const float4 gv = ((const float4*)gamma)[t];
  const float4 bv = ((const float4*)beta)[t];
  bf16x4_t o;
  o[0] = (bf16)((v.x - mu) * rs * gv.x + bv.x);
  o[1] = (bf16)((v.y - mu) * rs * gv.y + bv.y);
  o[2] = (bf16)((v.z - mu) * rs * gv.z + bv.z);
  o[3] = (bf16)((v.w - mu) * rs * gv.w + bv.w);
  *(bf16x4_t*)(kv_in + orow * 1024 + t * 4) = o;
  if (dual) {
    *(bf16x4_t*)(lnq + (size_t)lrow * 1024 + t * 4) = o;
  }
}

// ---------------- fused transpose+cast of the three weights ----------------
__global__ __launch_bounds__(256) void transpose_all(const float* __restrict__ Wq,
                                                     const float* __restrict__ Wkv,
                                                     const float* __restrict__ Wo,
                                                     bf16* __restrict__ Wq_t,
                                                     bf16* __restrict__ Wkv_t,
                                                     bf16* __restrict__ Wo_t) {
  __shared__ float tile[32][33];
  const int bid = blockIdx.x;
  const float* W;
  bf16* Wt;
  int C, t0;
  if (bid < 1024)      { W = Wq;  Wt = Wq_t;  C = 1024; t0 = bid; }
  else if (bid < 3072) { W = Wkv; Wt = Wkv_t; C = 2048; t0 = bid - 1024; }
  else                 { W = Wo;  Wt = Wo_t;  C = 1024; t0 = bid - 3072; }
  const int R = 1024;
  const int ntx = C >> 5;
  const int c0 = (t0 % ntx) * 32, r0 = (t0 / ntx) * 32;
  const int tx = threadIdx.x, ty = threadIdx.y;
#pragma unroll
  for (int j = 0; j < 4; ++j)
    tile[ty + j * 8][tx] = W[(size_t)(r0 + ty + j * 8) * C + c0 + tx];
  __syncthreads();
#pragma unroll
  for (int j = 0; j < 4; ++j)
    Wt[(size_t)(c0 + ty + j * 8) * R + r0 + tx] = (bf16)tile[tx][ty + j * 8];
}

// ---------------- small GEMM (128x128 tile): C = A * Bt^T, f32 row-major out ----------------
__global__ __launch_bounds__(256) void gemm_bt(const bf16* __restrict__ A,
                                               const bf16* __restrict__ Bt,
                                               float* __restrict__ Cf,
                                               int M, int N, int K) {
  __shared__ bf16 As[128 * 32];
  __shared__ bf16 Bs[128 * 32];
  const int tid = threadIdx.x;
  const int w = tid >> 6, l = tid & 63;
  const int lg = l >> 4, lr = l & 15;
  const int m0 = blockIdx.y * 128, n0 = blockIdx.x * 128;
  const int wm = w >> 1, wn = w & 1;

  f32x4_t acc[4][4];
#pragma unroll
  for (int i = 0; i < 4; ++i)
#pragma unroll
    for (int j = 0; j < 4; ++j)
      acc[i][j] = f32x4_t{0.f, 0.f, 0.f, 0.f};

  const int nk = K >> 5;
  for (int kt = 0; kt < nk; ++kt) {
    const int k0 = kt * 32;
#pragma unroll
    for (int j = 0; j < 2; ++j) {
      const int rb = j * 64 + w * 16;
      const int r = rb + (l >> 2);
      const int c = (l & 3) * 8;
      gload_lds16(A + (size_t)(m0 + r) * K + k0 + c, &As[rb * 32]);
      gload_lds16(Bt + (size_t)(n0 + r) * K + k0 + c, &Bs[rb * 32]);
    }
    __syncthreads();
    bf16x8_t af[4], bfr[4];
#pragma unroll
    for (int i = 0; i < 4; ++i) {
      af[i] = *(const bf16x8_t*)&As[(wm * 64 + i * 16 + lr) * 32 + lg * 8];
      bfr[i] = *(const bf16x8_t*)&Bs[(wn * 64 + i * 16 + lr) * 32 + lg * 8];
    }
#pragma unroll
    for (int mf = 0; mf < 4; ++mf)
#pragma unroll
      for (int nf = 0; nf < 4; ++nf)
        acc[mf][nf] = mfma16(af[mf], bfr[nf], acc[mf][nf]);
    __syncthreads();
  }

#pragma unroll
  for (int mf = 0; mf < 4; ++mf)
#pragma unroll
    for (int r = 0; r < 4; ++r) {
      const int grow = m0 + wm * 64 + mf * 16 + 4 * lg + r;
#pragma unroll
      for (int nf = 0; nf < 4; ++nf) {
        const int gcol = n0 + wn * 64 + nf * 16 + lr;
        Cf[(size_t)grow * N + gcol] = acc[mf][nf][r];
      }
    }
}

// ---------------- 256x256 4-phase GEMM: kv projection + fused q projection ----------------
// Blocks swz<1040: kv_in[33280,1024] x Wkv_t -> k[b,h,s,d] / v^T[b,h,d,s].
// Blocks swz>=1040 (8 tail blocks): lnq[512,1024] x Wq_t -> q[b,h,i,d].
// 8 waves (2M x 4N), BK=64, double-buffered swizzled LDS, ONE barrier per phase.
// B staged 1 tile ahead (ph0/ph1 -> nxt), A 2 tiles ahead (ph3 -> cur, safe after
// ph2's global lgkmcnt drain). vmcnt(4) once/tile leaves A(kt+2) in flight.
__global__ __launch_bounds__(512, 2) void gemm256_kv(const bf16* __restrict__ Akv,
                                                     const bf16* __restrict__ Aq,
                                                     const bf16* __restrict__ BtKV,
                                                     const bf16* __restrict__ BtQ,
                                                     bf16* __restrict__ Kout,
                                                     bf16* __restrict__ Vout,
                                                     bf16* __restrict__ Qout) {
  extern __shared__ char lds[];
  const int tid = threadIdx.x;
  const int w = tid >> 6, l = tid & 63;
  const int lr = l & 15, lg = l >> 4;
  const int wr = w >> 2, wc = w & 3;

  // XCD-aware bijective swizzle (1048 % 8 == 0)
  const int cpx = gridDim.x >> 3;
  const int swz = (blockIdx.x & 7) * cpx + (blockIdx.x >> 3);
  const bool isQ = swz >= 1040;
  const bf16* Ap;
  const bf16* Bp;
  int m0, n0;
  if (!isQ) {
    m0 = (swz >> 3) << 8;
    n0 = (swz & 7) << 8;
    Ap = Akv; Bp = BtKV;
  } else {
    const int qi = swz - 1040;
    m0 = (qi >> 2) << 8;
    n0 = (qi & 3) << 8;
    Ap = Aq; Bp = BtQ;
  }

  // stage one 128-row half (16 KB): 2 x global_load_lds(16B) per thread.
  // LDS dest linear; source col pre-swizzled so LDS content is XOR-swizzled.
  auto stage = [&](const bf16* __restrict__ G, int row0, int k0, char* base, int half) {
#pragma unroll
    for (int j = 0; j < 2; ++j) {
      const int r0 = half * 128 + (w * 2 + j) * 8;
      const int row = r0 + (l >> 3);
      const int col = ((l & 7) ^ (l >> 3)) * 8;
      gload_lds16(G + (size_t)(row0 + row) * 1024 + k0 + col, base + r0 * 128);
    }
  };
  auto rdA = [&](char* base, int mf, int ks) -> bf16x8_t {
    const int row = wr * 128 + mf * 16 + lr;
    int byte = row * 128 + (ks * 32 + lg * 8) * 2;
    byte ^= (row & 7) << 4;
    return *(const bf16x8_t*)(base + byte);
  };
  auto rdB = [&](char* base, int nf, int ks) -> bf16x8_t {
    const int row = wc * 64 + nf * 16 + lr;
    int byte = row * 128 + (ks * 32 + lg * 8) * 2;
    byte ^= (row & 7) << 4;
    return *(const bf16x8_t*)(base + byte);
  };

  f32x4_t acc[8][4];
#pragma unroll
  for (int i = 0; i < 8; ++i)
#pragma unroll
    for (int j = 0; j < 4; ++j)
      acc[i][j] = f32x4_t{0.f, 0.f, 0.f, 0.f};

  const int NK = 16;

  // prologue: A(0), B(0), A(1) — oldest-first so vmcnt(4) drains A(0)+B(0)
  stage(Ap, m0, 0, lds, 0);
  stage(Ap, m0, 0, lds, 1);
  stage(Bp, n0, 0, lds + 32768, 0);
  stage(Bp, n0, 0, lds + 32768, 1);
  stage(Ap, m0, 64, lds + 65536, 0);
  stage(Ap, m0, 64, lds + 65536, 1);
  asm volatile("s_waitcnt vmcnt(4)" ::: "memory");
  __builtin_amdgcn_s_barrier();

  bf16x8_t ra[4][2], rb[4][2];
  for (int kt = 0; kt < NK; ++kt) {
    const int cur = kt & 1, nxt = cur ^ 1;
    char* Ac = lds + cur * 65536;
    char* Bc = lds + 32768 + cur * 65536;
    char* Bn = lds + 32768 + nxt * 65536;
    const int k1 = (kt + 1) << 6, k2 = (kt + 2) << 6;

    // ---- phase 0: reads A mf0-3 + B nf0-1; stage B-h0(kt+1); 1 barrier; MFMA
#pragma unroll
    for (int mf = 0; mf < 4; ++mf) { ra[mf][0] = rdA(Ac, mf, 0); ra[mf][1] = rdA(Ac, mf, 1); }
#pragma unroll
    for (int nf = 0; nf < 2; ++nf) { rb[nf][0] = rdB(Bc, nf, 0); rb[nf][1] = rdB(Bc, nf, 1); }
    if (kt + 1 < NK) stage(Bp, n0, k1, Bn, 0);
    asm volatile("s_waitcnt lgkmcnt(0)" ::: "memory");
    __builtin_amdgcn_sched_barrier(0);
    __builtin_amdgcn_s_barrier();
    __builtin_amdgcn_s_setprio(1);
#pragma unroll
    for (int mf = 0; mf < 4; ++mf)
#pragma unroll
      for (int nf = 0; nf < 2; ++nf) {
        acc[mf][nf] = mfma16(ra[mf][0], rb[nf][0], acc[mf][nf]);
        acc[mf][nf] = mfma16(ra[mf][1], rb[nf][1], acc[mf][nf]);
      }
    __builtin_amdgcn_s_setprio(0);

    // ---- phase 1: reads B nf2-3; stage B-h1(kt+1); 1 barrier; MFMA
#pragma unroll
    for (int nf = 2; nf < 4; ++nf) { rb[nf][0] = rdB(Bc, nf, 0); rb[nf][1] = rdB(Bc, nf, 1); }
    if (kt + 1 < NK) stage(Bp, n0, k1, Bn, 1);
    asm volatile("s_waitcnt lgkmcnt(0)" ::: "memory");
    __builtin_amdgcn_sched_barrier(0);
    __builtin_amdgcn_s_barrier();
    __builtin_amdgcn_s_setprio(1);
#pragma unroll
    for (int mf = 0; mf < 4; ++mf)
#pragma unroll
      for (int nf = 2; nf < 4; ++nf) {
        acc[mf][nf] = mfma16(ra[mf][0], rb[nf][0], acc[mf][nf]);
        acc[mf][nf] = mfma16(ra[mf][1], rb[nf][1], acc[mf][nf]);
      }
    __builtin_amdgcn_s_setprio(0);

    // ---- phase 2: reads A mf4-7; 1 barrier; MFMA (all A-cur reads drained here)
#pragma unroll
    for (int mf = 0; mf < 4; ++mf) { ra[mf][0] = rdA(Ac, mf + 4, 0); ra[mf][1] = rdA(Ac, mf + 4, 1); }
    asm volatile("s_waitcnt lgkmcnt(0)" ::: "memory");
    __builtin_amdgcn_sched_barrier(0);
    __builtin_amdgcn_s_barrier();
    __builtin_amdgcn_s_setprio(1);
#pragma unroll
    for (int mf = 0; mf < 4; ++mf)
#pragma unroll
      for (int nf = 0; nf < 2; ++nf) {
        acc[mf + 4][nf] = mfma16(ra[mf][0], rb[nf][0], acc[mf + 4][nf]);
        acc[mf + 4][nf] = mfma16(ra[mf][1], rb[nf][1], acc[mf + 4][nf]);
      }
    __builtin_amdgcn_s_setprio(0);

    // ---- phase 3: stage A(kt+2) into A-cur (safe after ph2 barrier); vmcnt; barrier; MFMA
    if (kt + 2 < NK) { stage(Ap, m0, k2, Ac, 0); stage(Ap, m0, k2, Ac, 1); }
    if (kt + 2 < NK)
      asm volatile("s_waitcnt vmcnt(4)" ::: "memory");
    else
      asm volatile("s_waitcnt vmcnt(0)" ::: "memory");
    __builtin_amdgcn_sched_barrier(0);
    __builtin_amdgcn_s_barrier();
    __builtin_amdgcn_s_setprio(1);
#pragma unroll
    for (int mf = 0; mf < 4; ++mf)
#pragma unroll
      for (int nf = 2; nf < 4; ++nf) {
        acc[mf + 4][nf] = mfma16(ra[mf][0], rb[nf][0], acc[mf + 4][nf]);
        acc[mf + 4][nf] = mfma16(ra[mf][1], rb[nf][1], acc[mf + 4][nf]);
      }
    __builtin_amdgcn_s_setprio(0);
  }

  // epilogue scatter
  if (isQ) {
#pragma unroll
    for (int mf = 0; mf < 8; ++mf) {
      const int grow0 = m0 + wr * 128 + mf * 16 + 4 * lg;
#pragma unroll
      for (int nf = 0; nf < 4; ++nf) {
        const int gcol = n0 + wc * 64 + nf * 16 + lr;
        const int h = gcol >> 6, d = gcol & 63;
#pragma unroll
        for (int r = 0; r < 4; ++r) {
          const int grow = grow0 + r;
          const int b = grow >> 6, i = grow & 63;
          Qout[((size_t)((b * 16 + h) * 64 + i)) * 64 + d] = (bf16)acc[mf][nf][r];
        }
      }
    }
    return;
  }
#pragma unroll
  for (int mf = 0; mf < 8; ++mf) {
    const int grow0 = m0 + wr * 128 + mf * 16 + 4 * lg;
#pragma unroll
    for (int nf = 0; nf < 4; ++nf) {
      const int gcol = n0 + wc * 64 + nf * 16 + lr;
      if (gcol < 1024) {  // K half: k[b,h,s,d]
        const int h = gcol >> 6, d = gcol & 63;
#pragma unroll
        for (int r = 0; r < 4; ++r) {
          const int grow = grow0 + r;
          const int bb = grow / 4160, s = grow % 4160;
          Kout[((size_t)((bb * 16 + h) * 4160 + s)) * 64 + d] = (bf16)acc[mf][nf][r];
        }
      } else {  // V half: v^T[b,h,d,s], pack 4 consecutive s
        const int c2 = gcol - 1024, h = c2 >> 6, d = c2 & 63;
        const int bb = grow0 / 4160, s0 = grow0 % 4160;
        ushort4 u;
        u.x = bfbits(acc[mf][nf][0]);
        u.y = bfbits(acc[mf][nf][1]);
        u.z = bfbits(acc[mf][nf][2]);
        u.w = bfbits(acc[mf][nf][3]);
        *(ushort4*)&Vout[((size_t)((bb * 16 + h) * 64 + d)) * 4160 + s0] = u;
      }
    }
  }
}

// ---------------- flash attention partials: 4 independent waves/WG, 5 kv-chunks ----------------
// P-tile is PER-WAVE; same-wave ds_write->ds_read needs no block barrier (in-order
// LDS pipe + lgkmcnt). No __syncthreads: the 4 waves stream independently.
__global__ __launch_bounds__(256) void attn_part(const bf16* __restrict__ qb_,
                                                 const bf16* __restrict__ kb_,
                                                 const bf16* __restrict__ vb_,
                                                 float* __restrict__ ob,
                                                 float* __restrict__ mb,
                                                 float* __restrict__ lb) {
  const int c = blockIdx.x;   // 0..4
  const int bh = blockIdx.y;  // 0..127
  const int tid = threadIdx.x;
  const int wave = tid >> 6, l = tid & 63;
  const int lg = l >> 4, lr = l & 15;
  const int qr0 = wave * 16;

  const bf16* q = qb_ + ((size_t)bh * 64 + qr0) * 64;
  const bf16* Kp = kb_ + (size_t)bh * 4160 * 64;
  const bf16* Vt = vb_ + (size_t)bh * 64 * 4160;

  bf16x8_t qf[2];
#pragma unroll
  for (int kk = 0; kk < 2; ++kk)
    qf[kk] = *(const bf16x8_t*)(q + lr * 64 + kk * 32 + lg * 8);

  f32x4_t oacc[4];
  float m[4], lsum[4];
#pragma unroll
  for (int r = 0; r < 4; ++r) { m[r] = -1e30f; lsum[r] = 0.f; }
#pragma unroll
  for (int nf = 0; nf < 4; ++nf) oacc[nf] = f32x4_t{0.f, 0.f, 0.f, 0.f};

  __shared__ bf16 plds[4][16][72];
  bf16(*P)[72] = plds[wave];

  constexpr float inv = 1.0f / 64.0f;

  for (int kt = 0; kt < 13; ++kt) {
    const int key0 = c * 832 + kt * 64;
    f32x4_t sf[4];
#pragma unroll
    for (int nf = 0; nf < 4; ++nf) sf[nf] = f32x4_t{0.f, 0.f, 0.f, 0.f};
#pragma unroll
    for (int kk = 0; kk < 2; ++kk)
#pragma unroll
      for (int nf = 0; nf < 4; ++nf) {
        bf16x8_t kf = *(const bf16x8_t*)(Kp + (size_t)(key0 + nf * 16 + lr) * 64 + kk * 32 + lg * 8);
        sf[nf] = mfma16(qf[kk], kf, sf[nf]);
      }
    float corr[4];
#pragma unroll
    for (int r = 0; r < 4; ++r) {
      float t = fmaxf(fmaxf(sf[0][r], sf[1][r]), fmaxf(sf[2][r], sf[3][r])) * inv;
#pragma unroll
      for (int off = 1; off < 16; off <<= 1) t = fmaxf(t, __shfl_xor(t, off));
      const float mn = fmaxf(t, m[r]);
      corr[r] = __expf(m[r] - mn);
      m[r] = mn;
    }
    float rowsum[4] = {0.f, 0.f, 0.f, 0.f};
#pragma unroll
    for (int nf = 0; nf < 4; ++nf)
#pragma unroll
      for (int r = 0; r < 4; ++r) {
        const float p = __expf(sf[nf][r] * inv - m[r]);
        rowsum[r] += p;
        P[lg * 4 + r][nf * 16 + lr] = (bf16)p;
      }
#pragma unroll
    for (int r = 0; r < 4; ++r) {
      float t = rowsum[r];
#pragma unroll
      for (int off = 1; off < 16; off <<= 1) t += __shfl_xor(t, off);
      lsum[r] = lsum[r] * corr[r] + t;
    }
#pragma unroll
    for (int nf = 0; nf < 4; ++nf) {
      oacc[nf][0] *= corr[0];
      oacc[nf][1] *= corr[1];
      oacc[nf][2] *= corr[2];
      oacc[nf][3] *= corr[3];
    }
    asm volatile("s_waitcnt lgkmcnt(0)" ::: "memory");  // P writes visible to same wave
#pragma unroll
    for (int kk = 0; kk < 2; ++kk) {
      bf16x8_t pf = *(const bf16x8_t*)&P[lr][kk * 32 + lg * 8];
#pragma unroll
      for (int nf = 0; nf < 4; ++nf) {
        bf16x8_t vf = *(const bf16x8_t*)(Vt + (size_t)(nf * 16 + lr) * 4160 + key0 + kk * 32 + lg * 8);
        oacc[nf] = mfma16(pf, vf, oacc[nf]);
      }
    }
    asm volatile("s_waitcnt lgkmcnt(0)" ::: "memory");  // P reads done before next overwrite
  }

  // write partials (no 1/l normalization here)
#pragma unroll
  for (int nf = 0; nf < 4; ++nf)
#pragma unroll
    for (int r = 0; r < 4; ++r) {
      const int i = qr0 + lg * 4 + r;
      ob[((size_t)((bh * 64 + i) * 5 + c)) * 64 + nf * 16 + lr] = oacc[nf][r];
    }
  if (lr == 0) {
#pragma unroll
    for (int r = 0; r < 4; ++r) {
      const int i = qr0 + lg * 4 + r;
      mb[(bh * 64 + i) * 5 + c] = m[r];
      lb[(bh * 64 + i) * 5 + c] = lsum[r];
    }
  }
}

// ---------------- merge partials -> aout[b*64+i][h*64+d] bf16 ----------------
__global__ __launch_bounds__(256) void attn_merge(const float* __restrict__ ob,
                                                  const float* __restrict__ mb,
                                                  const float* __restrict__ lb,
                                                  bf16* __restrict__ aout) {
  const int j = blockIdx.x * 4 + (threadIdx.x >> 6);  // row 0..8191
  const int l = threadIdx.x & 63;
  float mv[5];
  float mx = -1e30f;
#pragma unroll
  for (int cc = 0; cc < 5; ++cc) { mv[cc] = mb[j * 5 + cc]; mx = fmaxf(mx, mv[cc]); }
  float L = 0.f, o = 0.f;
#pragma unroll
  for (int cc = 0; cc < 5; ++cc) {
    const float wgt = __expf(mv[cc] - mx);
    L += lb[j * 5 + cc] * wgt;
    o += wgt * ob[((size_t)(j * 5 + cc)) * 64 + l];
  }
  const int bh = j >> 6, i = j & 63, b = bh >> 4, h = bh & 15;
  aout[((size_t)(b * 64 + i)) * 1024 + h * 64 + l] = (bf16)(o / L);
}

// ---------------- launch ----------------
extern "C" void kernel_launch(void* const* d_in, const int* in_sizes, int n_in,
                              void* d_out, int out_size, void* d_ws, size_t ws_size,
                              hipStream_t stream) {
  (void)in_sizes; (void)n_in; (void)out_size; (void)ws_size;
  const float* x   = (const float*)d_in[0];
  const float* lat = (const float*)d_in[1];
  const float* g1  = (const float*)d_in[2];
  const float* b1  = (const float*)d_in[3];
  const float* g2  = (const float*)d_in[4];
  const float* b2  = (const float*)d_in[5];
  const float* Wq  = (const float*)d_in[6];
  const float* Wkv = (const float*)d_in[7];
  const float* Wo  = (const float*)d_in[8];
  float* out = (float*)d_out;

  char* ws = (char*)d_ws;
  size_t off = 0;
  auto alloc = [&](size_t bytes) {
    void* p = ws + off;
    off += (bytes + 255) & ~(size_t)255;
    return p;
  };
  bf16* kv_in = (bf16*)alloc(8ull * 4160 * 1024 * 2);     // concat(xn, ln) rows
  bf16* Wkv_t = (bf16*)alloc(2048ull * 1024 * 2);
  bf16* Wq_t  = (bf16*)alloc(1024ull * 1024 * 2);
  bf16* Wo_t  = (bf16*)alloc(1024ull * 1024 * 2);
  bf16* lnq   = (bf16*)alloc(512ull * 1024 * 2);
  bf16* qbuf  = (bf16*)alloc(512ull * 1024 * 2);          // [b,h,i,d]
  bf16* kbuf  = (bf16*)alloc(8ull * 16 * 4160 * 64 * 2);  // [b,h,s,d]
  bf16* vtbuf = (bf16*)alloc(8ull * 16 * 4160 * 64 * 2);  // [b,h,d,s]
  bf16* aout  = (bf16*)alloc(512ull * 1024 * 2);          // [b*64+i, h*64+d]

  // attention partials aliased into kv_in (dead after gemm256_kv; rewritten by LN each call)
  float* obuf = (float*)kv_in;           // 8192 * 5 * 64 f32
  float* mbuf = obuf + 8192ull * 5 * 64; // 8192 * 5
  float* lbuf = mbuf + 8192ull * 5;

  (void)hipFuncSetAttribute(reinterpret_cast<const void*>(gemm256_kv),
                            hipFuncAttributeMaxDynamicSharedMemorySize, 131072);

  transpose_all<<<4096, dim3(32, 8), 0, stream>>>(Wq, Wkv, Wo, Wq_t, Wkv_t, Wo_t);
  ln_all<<<33280, 256, 0, stream>>>(x, lat, g1, b1, g2, b2, kv_in, lnq);

  gemm256_kv<<<1048, 512, 131072, stream>>>(kv_in, lnq, Wkv_t, Wq_t, kbuf, vtbuf, qbuf);

  attn_part<<<dim3(5, 128), 256, 0, stream>>>(qbuf, kbuf, vtbuf, obuf, mbuf, lbuf);
  attn_merge<<<2048, 256, 0, stream>>>(obuf, mbuf, lbuf, aout);

  gemm_bt<<<dim3(1024 / 128, 512 / 128), 256, 0, stream>>>(aout, Wo_t, out, 512, 1024, 1024);
}

// Round 7
// 291.436 us; speedup vs baseline: 1.2677x; 1.0448x over previous
//
#include <hip/hip_runtime.h>

typedef __bf16 bf16;
typedef bf16 bf16x4_t __attribute__((ext_vector_type(4)));
typedef bf16 bf16x8_t __attribute__((ext_vector_type(8)));
typedef float f32x4_t __attribute__((ext_vector_type(4)));

#define DI __device__ __forceinline__

DI void gload_lds16(const void* g, void* l) {
  __builtin_amdgcn_global_load_lds((const __attribute__((address_space(1))) void*)g,
                                   (__attribute__((address_space(3))) void*)l, 16, 0, 0);
}

DI f32x4_t mfma16(bf16x8_t a, bf16x8_t b, f32x4_t c) {
  return __builtin_amdgcn_mfma_f32_16x16x32_bf16(a, b, c, 0, 0, 0);
}

DI unsigned short bfbits(float f) {
  bf16 h = (bf16)f;
  return __builtin_bit_cast(unsigned short, h);
}

// ---------------- fused prep: LN (1 wave/row) + weight transposes ----------------
// blocks [0,8320): LN of x rows (32768) then latent rows (512), 4 rows/block.
// blocks [8320,12416): 32x32 transpose tiles of Wq/Wkv/Wo.
__global__ __launch_bounds__(256) void prep_all(const float* __restrict__ x,
                                                const float* __restrict__ lat,
                                                const float* __restrict__ g1,
                                                const float* __restrict__ b1,
                                                const float* __restrict__ g2,
                                                const float* __restrict__ b2,
                                                const float* __restrict__ Wq,
                                                const float* __restrict__ Wkv,
                                                const float* __restrict__ Wo,
                                                bf16* __restrict__ kv_in,
                                                bf16* __restrict__ lnq,
                                                bf16* __restrict__ Wq_t,
                                                bf16* __restrict__ Wkv_t,
                                                bf16* __restrict__ Wo_t) {
  const int bid = blockIdx.x;
  const int t = threadIdx.x;
  if (bid < 8320) {
    const int wv = t >> 6, l = t & 63;
    const int row = bid * 4 + wv;
    const float* in;
    const float* gamma;
    const float* beta;
    size_t orow;
    bool dual = false;
    int lrow = 0;
    if (row < 32768) {
      in = x + (size_t)row * 1024;
      gamma = g1; beta = b1;
      orow = (size_t)(row >> 12) * 4160 + (row & 4095);
    } else {
      const int r = row - 32768;
      in = lat + (size_t)r * 1024;
      gamma = g2; beta = b2;
      orow = (size_t)(r >> 6) * 4160 + 4096 + (r & 63);
      dual = true;
      lrow = r;
    }
    float4 v[4];
    float s = 0.f, q = 0.f;
#pragma unroll
    for (int i = 0; i < 4; ++i) {
      v[i] = ((const float4*)in)[i * 64 + l];
      s += v[i].x + v[i].y + v[i].z + v[i].w;
      q += v[i].x * v[i].x + v[i].y * v[i].y + v[i].z * v[i].z + v[i].w * v[i].w;
    }
#pragma unroll
    for (int off = 1; off < 64; off <<= 1) {
      s += __shfl_xor(s, off);
      q += __shfl_xor(q, off);
    }
    const float mu = s * (1.f / 1024.f);
    const float var = q * (1.f / 1024.f) - mu * mu;
    const float rs = rsqrtf(var + 1e-5f);
#pragma unroll
    for (int i = 0; i < 4; ++i) {
      const float4 gv = ((const float4*)gamma)[i * 64 + l];
      const float4 bv = ((const float4*)beta)[i * 64 + l];
      bf16x4_t o;
      o[0] = (bf16)((v[i].x - mu) * rs * gv.x + bv.x);
      o[1] = (bf16)((v[i].y - mu) * rs * gv.y + bv.y);
      o[2] = (bf16)((v[i].z - mu) * rs * gv.z + bv.z);
      o[3] = (bf16)((v[i].w - mu) * rs * gv.w + bv.w);
      *(bf16x4_t*)(kv_in + orow * 1024 + i * 256 + l * 4) = o;
      if (dual) *(bf16x4_t*)(lnq + (size_t)lrow * 1024 + i * 256 + l * 4) = o;
    }
  } else {
    __shared__ float tile[32][33];
    const int b2i = bid - 8320;
    const float* W;
    bf16* Wt;
    int C, t0;
    if (b2i < 1024)      { W = Wq;  Wt = Wq_t;  C = 1024; t0 = b2i; }
    else if (b2i < 3072) { W = Wkv; Wt = Wkv_t; C = 2048; t0 = b2i - 1024; }
    else                 { W = Wo;  Wt = Wo_t;  C = 1024; t0 = b2i - 3072; }
    const int R = 1024;
    const int ntx = C >> 5;
    const int c0 = (t0 % ntx) * 32, r0 = (t0 / ntx) * 32;
    const int tx = t & 31, ty = t >> 5;
#pragma unroll
    for (int j = 0; j < 4; ++j)
      tile[ty + j * 8][tx] = W[(size_t)(r0 + ty + j * 8) * C + c0 + tx];
    __syncthreads();
#pragma unroll
    for (int j = 0; j < 4; ++j)
      Wt[(size_t)(c0 + ty + j * 8) * R + r0 + tx] = (bf16)tile[tx][ty + j * 8];
  }
}

// ---------------- small GEMM (128x128 tile): C = A * Bt^T, f32 row-major out ----------------
__global__ __launch_bounds__(256) void gemm_bt(const bf16* __restrict__ A,
                                               const bf16* __restrict__ Bt,
                                               float* __restrict__ Cf,
                                               int M, int N, int K) {
  __shared__ bf16 As[128 * 32];
  __shared__ bf16 Bs[128 * 32];
  const int tid = threadIdx.x;
  const int w = tid >> 6, l = tid & 63;
  const int lg = l >> 4, lr = l & 15;
  const int m0 = blockIdx.y * 128, n0 = blockIdx.x * 128;
  const int wm = w >> 1, wn = w & 1;

  f32x4_t acc[4][4];
#pragma unroll
  for (int i = 0; i < 4; ++i)
#pragma unroll
    for (int j = 0; j < 4; ++j)
      acc[i][j] = f32x4_t{0.f, 0.f, 0.f, 0.f};

  const int nk = K >> 5;
  for (int kt = 0; kt < nk; ++kt) {
    const int k0 = kt * 32;
#pragma unroll
    for (int j = 0; j < 2; ++j) {
      const int rb = j * 64 + w * 16;
      const int r = rb + (l >> 2);
      const int c = (l & 3) * 8;
      gload_lds16(A + (size_t)(m0 + r) * K + k0 + c, &As[rb * 32]);
      gload_lds16(Bt + (size_t)(n0 + r) * K + k0 + c, &Bs[rb * 32]);
    }
    __syncthreads();
    bf16x8_t af[4], bfr[4];
#pragma unroll
    for (int i = 0; i < 4; ++i) {
      af[i] = *(const bf16x8_t*)&As[(wm * 64 + i * 16 + lr) * 32 + lg * 8];
      bfr[i] = *(const bf16x8_t*)&Bs[(wn * 64 + i * 16 + lr) * 32 + lg * 8];
    }
#pragma unroll
    for (int mf = 0; mf < 4; ++mf)
#pragma unroll
      for (int nf = 0; nf < 4; ++nf)
        acc[mf][nf] = mfma16(af[mf], bfr[nf], acc[mf][nf]);
    __syncthreads();
  }

#pragma unroll
  for (int mf = 0; mf < 4; ++mf)
#pragma unroll
    for (int r = 0; r < 4; ++r) {
      const int grow = m0 + wm * 64 + mf * 16 + 4 * lg + r;
#pragma unroll
      for (int nf = 0; nf < 4; ++nf) {
        const int gcol = n0 + wn * 64 + nf * 16 + lr;
        Cf[(size_t)grow * N + gcol] = acc[mf][nf][r];
      }
    }
}

// ---------------- 256x256 4-phase GEMM: kv projection + fused q projection ----------------
__global__ __launch_bounds__(512, 2) void gemm256_kv(const bf16* __restrict__ Akv,
                                                     const bf16* __restrict__ Aq,
                                                     const bf16* __restrict__ BtKV,
                                                     const bf16* __restrict__ BtQ,
                                                     bf16* __restrict__ Kout,
                                                     bf16* __restrict__ Vout,
                                                     bf16* __restrict__ Qout) {
  extern __shared__ char lds[];
  const int tid = threadIdx.x;
  const int w = tid >> 6, l = tid & 63;
  const int lr = l & 15, lg = l >> 4;
  const int wr = w >> 2, wc = w & 3;

  const int cpx = gridDim.x >> 3;
  const int swz = (blockIdx.x & 7) * cpx + (blockIdx.x >> 3);
  const bool isQ = swz >= 1040;
  const bf16* Ap;
  const bf16* Bp;
  int m0, n0;
  if (!isQ) {
    m0 = (swz >> 3) << 8;
    n0 = (swz & 7) << 8;
    Ap = Akv; Bp = BtKV;
  } else {
    const int qi = swz - 1040;
    m0 = (qi >> 2) << 8;
    n0 = (qi & 3) << 8;
    Ap = Aq; Bp = BtQ;
  }

  auto stage = [&](const bf16* __restrict__ G, int row0, int k0, char* base, int half) {
#pragma unroll
    for (int j = 0; j < 2; ++j) {
      const int r0 = half * 128 + (w * 2 + j) * 8;
      const int row = r0 + (l >> 3);
      const int col = ((l & 7) ^ (l >> 3)) * 8;
      gload_lds16(G + (size_t)(row0 + row) * 1024 + k0 + col, base + r0 * 128);
    }
  };
  auto rdA = [&](char* base, int mf, int ks) -> bf16x8_t {
    const int row = wr * 128 + mf * 16 + lr;
    int byte = row * 128 + (ks * 32 + lg * 8) * 2;
    byte ^= (row & 7) << 4;
    return *(const bf16x8_t*)(base + byte);
  };
  auto rdB = [&](char* base, int nf, int ks) -> bf16x8_t {
    const int row = wc * 64 + nf * 16 + lr;
    int byte = row * 128 + (ks * 32 + lg * 8) * 2;
    byte ^= (row & 7) << 4;
    return *(const bf16x8_t*)(base + byte);
  };

  f32x4_t acc[8][4];
#pragma unroll
  for (int i = 0; i < 8; ++i)
#pragma unroll
    for (int j = 0; j < 4; ++j)
      acc[i][j] = f32x4_t{0.f, 0.f, 0.f, 0.f};

  const int NK = 16;

  stage(Ap, m0, 0, lds, 0);
  stage(Ap, m0, 0, lds, 1);
  stage(Bp, n0, 0, lds + 32768, 0);
  stage(Bp, n0, 0, lds + 32768, 1);
  stage(Ap, m0, 64, lds + 65536, 0);
  stage(Ap, m0, 64, lds + 65536, 1);
  asm volatile("s_waitcnt vmcnt(4)" ::: "memory");
  __builtin_amdgcn_s_barrier();

  bf16x8_t ra[4][2], rb[4][2];
  for (int kt = 0; kt < NK; ++kt) {
    const int cur = kt & 1, nxt = cur ^ 1;
    char* Ac = lds + cur * 65536;
    char* Bc = lds + 32768 + cur * 65536;
    char* Bn = lds + 32768 + nxt * 65536;
    const int k1 = (kt + 1) << 6, k2 = (kt + 2) << 6;

    // ---- phase 0
#pragma unroll
    for (int mf = 0; mf < 4; ++mf) { ra[mf][0] = rdA(Ac, mf, 0); ra[mf][1] = rdA(Ac, mf, 1); }
#pragma unroll
    for (int nf = 0; nf < 2; ++nf) { rb[nf][0] = rdB(Bc, nf, 0); rb[nf][1] = rdB(Bc, nf, 1); }
    if (kt + 1 < NK) stage(Bp, n0, k1, Bn, 0);
    asm volatile("s_waitcnt lgkmcnt(0)" ::: "memory");
    __builtin_amdgcn_sched_barrier(0);
    __builtin_amdgcn_s_barrier();
    __builtin_amdgcn_s_setprio(1);
#pragma unroll
    for (int mf = 0; mf < 4; ++mf)
#pragma unroll
      for (int nf = 0; nf < 2; ++nf) {
        acc[mf][nf] = mfma16(ra[mf][0], rb[nf][0], acc[mf][nf]);
        acc[mf][nf] = mfma16(ra[mf][1], rb[nf][1], acc[mf][nf]);
      }
    __builtin_amdgcn_s_setprio(0);

    // ---- phase 1
#pragma unroll
    for (int nf = 2; nf < 4; ++nf) { rb[nf][0] = rdB(Bc, nf, 0); rb[nf][1] = rdB(Bc, nf, 1); }
    if (kt + 1 < NK) stage(Bp, n0, k1, Bn, 1);
    asm volatile("s_waitcnt lgkmcnt(0)" ::: "memory");
    __builtin_amdgcn_sched_barrier(0);
    __builtin_amdgcn_s_barrier();
    __builtin_amdgcn_s_setprio(1);
#pragma unroll
    for (int mf = 0; mf < 4; ++mf)
#pragma unroll
      for (int nf = 2; nf < 4; ++nf) {
        acc[mf][nf] = mfma16(ra[mf][0], rb[nf][0], acc[mf][nf]);
        acc[mf][nf] = mfma16(ra[mf][1], rb[nf][1], acc[mf][nf]);
      }
    __builtin_amdgcn_s_setprio(0);

    // ---- phase 2
#pragma unroll
    for (int mf = 0; mf < 4; ++mf) { ra[mf][0] = rdA(Ac, mf + 4, 0); ra[mf][1] = rdA(Ac, mf + 4, 1); }
    asm volatile("s_waitcnt lgkmcnt(0)" ::: "memory");
    __builtin_amdgcn_sched_barrier(0);
    __builtin_amdgcn_s_barrier();
    __builtin_amdgcn_s_setprio(1);
#pragma unroll
    for (int mf = 0; mf < 4; ++mf)
#pragma unroll
      for (int nf = 0; nf < 2; ++nf) {
        acc[mf + 4][nf] = mfma16(ra[mf][0], rb[nf][0], acc[mf + 4][nf]);
        acc[mf + 4][nf] = mfma16(ra[mf][1], rb[nf][1], acc[mf + 4][nf]);
      }
    __builtin_amdgcn_s_setprio(0);

    // ---- phase 3
    if (kt + 2 < NK) { stage(Ap, m0, k2, Ac, 0); stage(Ap, m0, k2, Ac, 1); }
    if (kt + 2 < NK)
      asm volatile("s_waitcnt vmcnt(4)" ::: "memory");
    else
      asm volatile("s_waitcnt vmcnt(0)" ::: "memory");
    __builtin_amdgcn_sched_barrier(0);
    __builtin_amdgcn_s_barrier();
    __builtin_amdgcn_s_setprio(1);
#pragma unroll
    for (int mf = 0; mf < 4; ++mf)
#pragma unroll
      for (int nf = 2; nf < 4; ++nf) {
        acc[mf + 4][nf] = mfma16(ra[mf][0], rb[nf][0], acc[mf + 4][nf]);
        acc[mf + 4][nf] = mfma16(ra[mf][1], rb[nf][1], acc[mf + 4][nf]);
      }
    __builtin_amdgcn_s_setprio(0);
  }

  if (isQ) {
#pragma unroll
    for (int mf = 0; mf < 8; ++mf) {
      const int grow0 = m0 + wr * 128 + mf * 16 + 4 * lg;
#pragma unroll
      for (int nf = 0; nf < 4; ++nf) {
        const int gcol = n0 + wc * 64 + nf * 16 + lr;
        const int h = gcol >> 6, d = gcol & 63;
#pragma unroll
        for (int r = 0; r < 4; ++r) {
          const int grow = grow0 + r;
          const int b = grow >> 6, i = grow & 63;
          Qout[((size_t)((b * 16 + h) * 64 + i)) * 64 + d] = (bf16)acc[mf][nf][r];
        }
      }
    }
    return;
  }
#pragma unroll
  for (int mf = 0; mf < 8; ++mf) {
    const int grow0 = m0 + wr * 128 + mf * 16 + 4 * lg;
#pragma unroll
    for (int nf = 0; nf < 4; ++nf) {
      const int gcol = n0 + wc * 64 + nf * 16 + lr;
      if (gcol < 1024) {
        const int h = gcol >> 6, d = gcol & 63;
#pragma unroll
        for (int r = 0; r < 4; ++r) {
          const int grow = grow0 + r;
          const int bb = grow / 4160, s = grow % 4160;
          Kout[((size_t)((bb * 16 + h) * 4160 + s)) * 64 + d] = (bf16)acc[mf][nf][r];
        }
      } else {
        const int c2 = gcol - 1024, h = c2 >> 6, d = c2 & 63;
        const int bb = grow0 / 4160, s0 = grow0 % 4160;
        ushort4 u;
        u.x = bfbits(acc[mf][nf][0]);
        u.y = bfbits(acc[mf][nf][1]);
        u.z = bfbits(acc[mf][nf][2]);
        u.w = bfbits(acc[mf][nf][3]);
        *(ushort4*)&Vout[((size_t)((bb * 16 + h) * 64 + d)) * 4160 + s0] = u;
      }
    }
  }
}

// ---------------- flash attention partials: 4 independent waves/WG, 5 kv-chunks ----------------
// Load schedule: K refilled in-place right after its last QK use (latency hides
// under softmax+P+PV); V issued BEFORE the P-drain (the asm "memory" clobber
// otherwise pins it after). P-tile per-wave; no block barriers.
__global__ __launch_bounds__(256) void attn_part(const bf16* __restrict__ qb_,
                                                 const bf16* __restrict__ kb_,
                                                 const bf16* __restrict__ vb_,
                                                 float* __restrict__ ob,
                                                 float* __restrict__ mb,
                                                 float* __restrict__ lb) {
  const int c = blockIdx.x;   // 0..4
  const int bh = blockIdx.y;  // 0..127
  const int tid = threadIdx.x;
  const int wave = tid >> 6, l = tid & 63;
  const int lg = l >> 4, lr = l & 15;
  const int qr0 = wave * 16;

  const bf16* q = qb_ + ((size_t)bh * 64 + qr0) * 64;
  const bf16* Kp = kb_ + (size_t)bh * 4160 * 64;
  const bf16* Vt = vb_ + (size_t)bh * 64 * 4160;

  bf16x8_t qf[2];
#pragma unroll
  for (int kk = 0; kk < 2; ++kk)
    qf[kk] = *(const bf16x8_t*)(q + lr * 64 + kk * 32 + lg * 8);

  f32x4_t oacc[4];
  float m[4], lsum[4];
#pragma unroll
  for (int r = 0; r < 4; ++r) { m[r] = -1e30f; lsum[r] = 0.f; }
#pragma unroll
  for (int nf = 0; nf < 4; ++nf) oacc[nf] = f32x4_t{0.f, 0.f, 0.f, 0.f};

  __shared__ bf16 plds[4][16][72];
  bf16(*P)[72] = plds[wave];

  constexpr float inv = 1.0f / 64.0f;

  bf16x8_t kf[2][4];
  auto ldK = [&](int key0) {
#pragma unroll
    for (int kk = 0; kk < 2; ++kk)
#pragma unroll
      for (int nf = 0; nf < 4; ++nf)
        kf[kk][nf] = *(const bf16x8_t*)(Kp + (size_t)(key0 + nf * 16 + lr) * 64 + kk * 32 + lg * 8);
  };

  ldK(c * 832);
  for (int kt = 0; kt < 13; ++kt) {
    const int key0 = c * 832 + kt * 64;
    f32x4_t sf[4];
#pragma unroll
    for (int nf = 0; nf < 4; ++nf) sf[nf] = f32x4_t{0.f, 0.f, 0.f, 0.f};
#pragma unroll
    for (int kk = 0; kk < 2; ++kk)
#pragma unroll
      for (int nf = 0; nf < 4; ++nf)
        sf[nf] = mfma16(qf[kk], kf[kk][nf], sf[nf]);
    // refill K in place for next tile; completes under softmax+P+PV
    if (kt + 1 < 13) ldK(key0 + 64);
    float corr[4];
#pragma unroll
    for (int r = 0; r < 4; ++r) {
      float t = fmaxf(fmaxf(sf[0][r], sf[1][r]), fmaxf(sf[2][r], sf[3][r])) * inv;
#pragma unroll
      for (int off = 1; off < 16; off <<= 1) t = fmaxf(t, __shfl_xor(t, off));
      const float mn = fmaxf(t, m[r]);
      corr[r] = __expf(m[r] - mn);
      m[r] = mn;
    }
    float rowsum[4] = {0.f, 0.f, 0.f, 0.f};
#pragma unroll
    for (int nf = 0; nf < 4; ++nf)
#pragma unroll
      for (int r = 0; r < 4; ++r) {
        const float p = __expf(sf[nf][r] * inv - m[r]);
        rowsum[r] += p;
        P[lg * 4 + r][nf * 16 + lr] = (bf16)p;
      }
#pragma unroll
    for (int r = 0; r < 4; ++r) {
      float t = rowsum[r];
#pragma unroll
      for (int off = 1; off < 16; off <<= 1) t += __shfl_xor(t, off);
      lsum[r] = lsum[r] * corr[r] + t;
    }
#pragma unroll
    for (int nf = 0; nf < 4; ++nf) {
      oacc[nf][0] *= corr[0];
      oacc[nf][1] *= corr[1];
      oacc[nf][2] *= corr[2];
      oacc[nf][3] *= corr[3];
    }
    // issue V loads BEFORE the drain so they fly during the wait
    bf16x8_t vf[2][4];
#pragma unroll
    for (int kk = 0; kk < 2; ++kk)
#pragma unroll
      for (int nf = 0; nf < 4; ++nf)
        vf[kk][nf] = *(const bf16x8_t*)(Vt + (size_t)(nf * 16 + lr) * 4160 + key0 + kk * 32 + lg * 8);
    asm volatile("s_waitcnt lgkmcnt(0)" ::: "memory");  // P writes visible to same wave
#pragma unroll
    for (int kk = 0; kk < 2; ++kk) {
      bf16x8_t pf = *(const bf16x8_t*)&P[lr][kk * 32 + lg * 8];
#pragma unroll
      for (int nf = 0; nf < 4; ++nf)
        oacc[nf] = mfma16(pf, vf[kk][nf], oacc[nf]);
    }
    asm volatile("s_waitcnt lgkmcnt(0)" ::: "memory");  // P reads done before next overwrite
  }

#pragma unroll
  for (int nf = 0; nf < 4; ++nf)
#pragma unroll
    for (int r = 0; r < 4; ++r) {
      const int i = qr0 + lg * 4 + r;
      ob[((size_t)((bh * 64 + i) * 5 + c)) * 64 + nf * 16 + lr] = oacc[nf][r];
    }
  if (lr == 0) {
#pragma unroll
    for (int r = 0; r < 4; ++r) {
      const int i = qr0 + lg * 4 + r;
      mb[(bh * 64 + i) * 5 + c] = m[r];
      lb[(bh * 64 + i) * 5 + c] = lsum[r];
    }
  }
}

// ---------------- merge partials -> aout[b*64+i][h*64+d] bf16 ----------------
__global__ __launch_bounds__(256) void attn_merge(const float* __restrict__ ob,
                                                  const float* __restrict__ mb,
                                                  const float* __restrict__ lb,
                                                  bf16* __restrict__ aout) {
  const int j = blockIdx.x * 4 + (threadIdx.x >> 6);  // row 0..8191
  const int l = threadIdx.x & 63;
  float mv[5];
  float mx = -1e30f;
#pragma unroll
  for (int cc = 0; cc < 5; ++cc) { mv[cc] = mb[j * 5 + cc]; mx = fmaxf(mx, mv[cc]); }
  float L = 0.f, o = 0.f;
#pragma unroll
  for (int cc = 0; cc < 5; ++cc) {
    const float wgt = __expf(mv[cc] - mx);
    L += lb[j * 5 + cc] * wgt;
    o += wgt * ob[((size_t)(j * 5 + cc)) * 64 + l];
  }
  const int bh = j >> 6, i = j & 63, b = bh >> 4, h = bh & 15;
  aout[((size_t)(b * 64 + i)) * 1024 + h * 64 + l] = (bf16)(o / L);
}

// ---------------- launch ----------------
extern "C" void kernel_launch(void* const* d_in, const int* in_sizes, int n_in,
                              void* d_out, int out_size, void* d_ws, size_t ws_size,
                              hipStream_t stream) {
  (void)in_sizes; (void)n_in; (void)out_size; (void)ws_size;
  const float* x   = (const float*)d_in[0];
  const float* lat = (const float*)d_in[1];
  const float* g1  = (const float*)d_in[2];
  const float* b1  = (const float*)d_in[3];
  const float* g2  = (const float*)d_in[4];
  const float* b2  = (const float*)d_in[5];
  const float* Wq  = (const float*)d_in[6];
  const float* Wkv = (const float*)d_in[7];
  const float* Wo  = (const float*)d_in[8];
  float* out = (float*)d_out;

  char* ws = (char*)d_ws;
  size_t off = 0;
  auto alloc = [&](size_t bytes) {
    void* p = ws + off;
    off += (bytes + 255) & ~(size_t)255;
    return p;
  };
  bf16* kv_in = (bf16*)alloc(8ull * 4160 * 1024 * 2);     // concat(xn, ln) rows
  bf16* Wkv_t = (bf16*)alloc(2048ull * 1024 * 2);
  bf16* Wq_t  = (bf16*)alloc(1024ull * 1024 * 2);
  bf16* Wo_t  = (bf16*)alloc(1024ull * 1024 * 2);
  bf16* lnq   = (bf16*)alloc(512ull * 1024 * 2);
  bf16* qbuf  = (bf16*)alloc(512ull * 1024 * 2);          // [b,h,i,d]
  bf16* kbuf  = (bf16*)alloc(8ull * 16 * 4160 * 64 * 2);  // [b,h,s,d]
  bf16* vtbuf = (bf16*)alloc(8ull * 16 * 4160 * 64 * 2);  // [b,h,d,s]
  bf16* aout  = (bf16*)alloc(512ull * 1024 * 2);          // [b*64+i, h*64+d]

  // attention partials aliased into kv_in (dead after gemm256_kv)
  float* obuf = (float*)kv_in;           // 8192 * 5 * 64 f32
  float* mbuf = obuf + 8192ull * 5 * 64; // 8192 * 5
  float* lbuf = mbuf + 8192ull * 5;

  (void)hipFuncSetAttribute(reinterpret_cast<const void*>(gemm256_kv),
                            hipFuncAttributeMaxDynamicSharedMemorySize, 131072);

  prep_all<<<12416, 256, 0, stream>>>(x, lat, g1, b1, g2, b2, Wq, Wkv, Wo,
                                      kv_in, lnq, Wq_t, Wkv_t, Wo_t);

  gemm256_kv<<<1048, 512, 131072, stream>>>(kv_in, lnq, Wkv_t, Wq_t, kbuf, vtbuf, qbuf);

  attn_part<<<dim3(5, 128), 256, 0, stream>>>(qbuf, kbuf, vtbuf, obuf, mbuf, lbuf);
  attn_merge<<<2048, 256, 0, stream>>>(obuf, mbuf, lbuf, aout);

  gemm_bt<<<dim3(1024 / 128, 512 / 128), 256, 0, stream>>>(aout, Wo_t, out, 512, 1024, 1024);
}